// Round 11
// baseline (190.464 us; speedup 1.0000x reference)
//
#include <hip/hip_runtime.h>
#include <math.h>

#define T_TOK 8192
#define A_DIM 1024
#define E_DIM 512
#define S_SPAN 32768
#define HID 150

typedef __attribute__((ext_vector_type(8))) short short8;
typedef __attribute__((ext_vector_type(4))) float f32x4;
typedef __attribute__((ext_vector_type(4))) unsigned int u32x4;
typedef __attribute__((ext_vector_type(4))) unsigned short u16x4;

__device__ __forceinline__ unsigned short f2bf(float f) {
    unsigned int u = __builtin_bit_cast(unsigned int, f);
    u += 0x7FFFu + ((u >> 16) & 1u);          // RNE
    return (unsigned short)(u >> 16);
}
__device__ __forceinline__ float bf2f(unsigned int h16) {
    unsigned int u = h16 << 16;
    return __builtin_bit_cast(float, u);
}

// ---------------------------------------------------------------------------
// fused prep: input cast (fp32->bf16) + 6 weight transposes + width proj
// ---------------------------------------------------------------------------
#define NS4 (T_TOK * A_DIM / 4)   // 2097152
#define NE4 (T_TOK * E_DIM / 4)   // 1048576
#define NCAST ((NS4 + NE4) / 256) // 12288 exactly

struct WConv { const float* src; unsigned short* dst; int K0; int Kpad; int nblk; };
struct PrepTab {
    const float* s; const float* e; unsigned short* sd; unsigned short* ed;
    WConv g[6];
    const float* wt; const float* Ws1w; float* PW;
};

__global__ __launch_bounds__(256) void prep_kernel(PrepTab tab) {
    int b = blockIdx.x;
    if (b < NCAST) {
        int idx = b * 256 + threadIdx.x;
        const float* src; unsigned short* dst;
        if (idx < NS4) { src = tab.s; dst = tab.sd; }
        else { idx -= NS4; src = tab.e; dst = tab.ed; }
        f32x4 v = *(const f32x4*)(src + (size_t)idx * 4);
        u16x4 o;
        o.x = f2bf(v.x); o.y = f2bf(v.y); o.z = f2bf(v.z); o.w = f2bf(v.w);
        *(u16x4*)(dst + (size_t)idx * 4) = o;
        return;
    }
    b -= NCAST;
    #pragma unroll
    for (int gi = 0; gi < 6; ++gi) {
        if (b < tab.g[gi].nblk) {
            int idx = b * 256 + threadIdx.x;               // idx = k*160 + j
            int Kpad = tab.g[gi].Kpad;
            if (idx < Kpad * 160) {
                int k = idx / 160, j = idx - k * 160;
                float v = (j < HID && k < tab.g[gi].K0)
                          ? tab.g[gi].src[(size_t)k * HID + j] : 0.f;   // coalesced read
                tab.g[gi].dst[(size_t)j * Kpad + k] = f2bf(v);          // scattered write
            }
            return;
        }
        b -= tab.g[gi].nblk;
    }
    // width projection: 9 blocks
    int j = threadIdx.x;
    if (j < HID) {
        float acc = 0.f;
        for (int k = 0; k < 20; ++k)
            acc = fmaf(tab.wt[b * 20 + k], tab.Ws1w[k * HID + j], acc);
        tab.PW[b * HID + j] = acc;
    }
}

// ---------------------------------------------------------------------------
// unified MFMA GEMM (R9 structure): dbuf BK=64, LDW=72 (46 KB, 3 blocks/CU)
// ---------------------------------------------------------------------------
struct GG {
    const unsigned short* A; int lda;
    const unsigned short* W; int K; int nrb;
    unsigned short* outh; int ldo;
    const float* bias; int relu;
    const float* dotv; const float* dotb; float* dotout;
};
struct GTab { GG g[4]; int ng; };

template <int TAG>
__global__ __launch_bounds__(256) void gemm_fused(GTab tab) {
    constexpr int LDW = 72;
    __shared__ unsigned short WtL[2][160 * LDW];

    int b = blockIdx.x;
    int gi = 0;
    while (gi < tab.ng - 1 && b >= tab.g[gi].nrb) { b -= tab.g[gi].nrb; ++gi; }
    const GG G = tab.g[gi];

    const int tid = threadIdx.x;
    const int wid = tid >> 6;
    const int lane = tid & 63;
    const int l15 = lane & 15;
    const int quad = lane >> 4;
    const int row0 = b * 64 + wid * 16 + l15;
    const int K = G.K;
    const int nch = K >> 6;
    const unsigned short* Arow = G.A + (size_t)row0 * G.lda;

    u32x4 stg[5];
    int sn[5], sk[5];
    #pragma unroll
    for (int i = 0; i < 5; ++i) { int u = tid + i * 256; sn[i] = u >> 3; sk[i] = (u & 7) * 8; }

    f32x4 acc[10];
    #pragma unroll
    for (int nt = 0; nt < 10; ++nt) acc[nt] = (f32x4){0.f, 0.f, 0.f, 0.f};

    #pragma unroll
    for (int i = 0; i < 5; ++i)
        stg[i] = *(const u32x4*)(G.W + (size_t)sn[i] * K + sk[i]);
    short8 avc0 = *(const short8*)(Arow + quad * 8);
    short8 avc1 = *(const short8*)(Arow + 32 + quad * 8);
    #pragma unroll
    for (int i = 0; i < 5; ++i)
        *(u32x4*)&WtL[0][sn[i] * LDW + sk[i]] = stg[i];
    __syncthreads();

    for (int c = 0; c < nch; ++c) {
        const int pb = c & 1;
        short8 avn0, avn1;
        const bool more = (c + 1 < nch);
        if (more) {
            const int kn = (c + 1) << 6;
            #pragma unroll
            for (int i = 0; i < 5; ++i)
                stg[i] = *(const u32x4*)(G.W + (size_t)sn[i] * K + kn + sk[i]);
            avn0 = *(const short8*)(Arow + kn + quad * 8);
            avn1 = *(const short8*)(Arow + kn + 32 + quad * 8);
        }
        #pragma unroll
        for (int nt = 0; nt < 10; ++nt) {
            short8 bv0 = *(const short8*)&WtL[pb][(nt * 16 + l15) * LDW + quad * 8];
            acc[nt] = __builtin_amdgcn_mfma_f32_16x16x32_bf16(avc0, bv0, acc[nt], 0, 0, 0);
            short8 bv1 = *(const short8*)&WtL[pb][(nt * 16 + l15) * LDW + 32 + quad * 8];
            acc[nt] = __builtin_amdgcn_mfma_f32_16x16x32_bf16(avc1, bv1, acc[nt], 0, 0, 0);
        }
        if (more) {
            #pragma unroll
            for (int i = 0; i < 5; ++i)
                *(u32x4*)&WtL[pb ^ 1][sn[i] * LDW + sk[i]] = stg[i];
            avc0 = avn0; avc1 = avn1;
        }
        __syncthreads();
    }

    const int rbase = b * 64 + wid * 16 + quad * 4;
    if (G.dotout) {
        float part[4] = {0.f, 0.f, 0.f, 0.f};
        #pragma unroll
        for (int nt = 0; nt < 10; ++nt) {
            int col = nt * 16 + l15;
            float bv_ = (col < HID) ? G.bias[col] : 0.f;
            float vv = (col < HID) ? G.dotv[col] : 0.f;
            #pragma unroll
            for (int r = 0; r < 4; ++r)
                part[r] += fmaxf(acc[nt][r] + bv_, 0.f) * vv;
        }
        #pragma unroll
        for (int r = 0; r < 4; ++r) {
            float p = part[r];
            #pragma unroll
            for (int off = 1; off < 16; off <<= 1) p += __shfl_xor(p, off);
            if (l15 == 0) G.dotout[rbase + r] = p + G.dotb[0];
        }
    } else {
        #pragma unroll
        for (int nt = 0; nt < 10; ++nt) {
            int col = nt * 16 + l15;
            float bv_ = (G.bias != nullptr && col < HID) ? G.bias[col] : 0.f;
            #pragma unroll
            for (int r = 0; r < 4; ++r) {
                int row = rbase + r;
                float v = acc[nt][r] + bv_;
                if (G.relu) v = fmaxf(v, 0.f);
                G.outh[(size_t)row * G.ldo + col] = f2bf(v);
            }
        }
    }
}

// ---------------------------------------------------------------------------
// merged span layer1 + layer2 GEMM + layer3 dot. 64 spans per block.
// phase 1: each wave computes h1 (bf16) for 16 spans -> LDS A-tile [64][200]
//          (k-cols 150..191 zeroed; W pad rows are zero but LDS is uninit).
// phase 2: K=192 dbuf GEMM from LDS A-tile + fused dot epilogue -> out.
// LDS: 46.1 + 25.6 = 71.7 KB -> 2 blocks/CU; grid 512 exactly resident.
// ---------------------------------------------------------------------------
__global__ __launch_bounds__(256) void span_gemm_kernel(
        const float* __restrict__ attns,
        const int* __restrict__ starts, const int* __restrict__ lens,
        const unsigned short* __restrict__ Ps, const unsigned short* __restrict__ Pe,
        const unsigned short* __restrict__ Pm,
        const float* __restrict__ PW, const float* __restrict__ bs1,
        const unsigned short* __restrict__ W, const float* __restrict__ bs2,
        const float* __restrict__ Ws3, const float* __restrict__ bs3,
        float* __restrict__ out) {
    constexpr int LDW = 72;
    constexpr int LDA = 200;   // 400 B rows: 16B-aligned, 2-way bank alias only
    __shared__ unsigned short WtL[2][160 * LDW];
    __shared__ unsigned short Atile[64 * LDA];

    const int tid = threadIdx.x;
    const int wid = tid >> 6;
    const int lane = tid & 63;
    const int l15 = lane & 15;
    const int quad = lane >> 4;
    constexpr int K = 192;

    // issue W chunk-0 staging loads early (written to LDS after phase 1)
    u32x4 stg[5];
    int sn[5], sk[5];
    #pragma unroll
    for (int i = 0; i < 5; ++i) { int u = tid + i * 256; sn[i] = u >> 3; sk[i] = (u & 7) * 8; }
    #pragma unroll
    for (int i = 0; i < 5; ++i)
        stg[i] = *(const u32x4*)(W + (size_t)sn[i] * K + sk[i]);

    // ---- phase 1: 16 spans per wave ----
    for (int sp = 0; sp < 16; ++sp) {
        const int sl = wid * 16 + sp;
        const int s = blockIdx.x * 64 + sl;
        const int start = starts[s];
        const int len = lens[s];

        const int iv = min(start + lane, T_TOK - 1);
        float a = (lane <= len) ? attns[iv] : -INFINITY;
        float m = a;
        #pragma unroll
        for (int off = 32; off; off >>= 1) m = fmaxf(m, __shfl_xor(m, off));
        float e = (lane <= len) ? __expf(a - m) : 0.f;
        float ssum = e;
        #pragma unroll
        for (int off = 32; off; off >>= 1) ssum += __shfl_xor(ssum, off);
        float wv = e / ssum;

        float wl[10]; int il[10];
        #pragma unroll
        for (int l = 0; l < 10; ++l) { wl[l] = __shfl(wv, l); il[l] = __shfl(iv, l); }

        const int end = start + len;
        const int width = len + 1;
        const int bucket = (width >= 1) + (width >= 2) + (width >= 3) + (width >= 4) +
                           (width >= 8) + (width >= 16) + (width >= 32) + (width >= 64);

        const unsigned short* ps = Ps + (size_t)start * 160;
        const unsigned short* pe = Pe + (size_t)end * 160;
        const float* pw = PW + bucket * HID;

        // p<75: compute h1 pair; 75<=p<96: zero pad (k-cols 150..190)
        for (int p = lane; p < 96; p += 64) {
            unsigned int packed = 0;
            if (p < 75) {
                const int j = 2 * p;
                unsigned int u0 = *(const unsigned int*)(ps + j);
                unsigned int u1 = *(const unsigned int*)(pe + j);
                float a0 = bs1[j]     + bf2f(u0 & 0xffff) + bf2f(u1 & 0xffff) + pw[j];
                float a1 = bs1[j + 1] + bf2f(u0 >> 16)    + bf2f(u1 >> 16)    + pw[j + 1];
                #pragma unroll
                for (int l = 0; l < 10; ++l) {
                    unsigned int um = *(const unsigned int*)(Pm + (size_t)il[l] * 160 + j);
                    a0 = fmaf(wl[l], bf2f(um & 0xffff), a0);
                    a1 = fmaf(wl[l], bf2f(um >> 16), a1);
                }
                packed = (unsigned int)f2bf(fmaxf(a0, 0.f)) |
                         ((unsigned int)f2bf(fmaxf(a1, 0.f)) << 16);
            }
            *(unsigned int*)&Atile[sl * LDA + 2 * p] = packed;
        }
    }

    // write W chunk 0 to LDS buf0; barrier covers Atile + WtL
    #pragma unroll
    for (int i = 0; i < 5; ++i)
        *(u32x4*)&WtL[0][sn[i] * LDW + sk[i]] = stg[i];
    __syncthreads();

    // ---- phase 2: K=192 GEMM from LDS A-tile ----
    const int arow = wid * 16 + l15;
    f32x4 acc[10];
    #pragma unroll
    for (int nt = 0; nt < 10; ++nt) acc[nt] = (f32x4){0.f, 0.f, 0.f, 0.f};

    for (int c = 0; c < 3; ++c) {
        const int pb = c & 1;
        const bool more = (c + 1 < 3);
        if (more) {
            const int kn = (c + 1) << 6;
            #pragma unroll
            for (int i = 0; i < 5; ++i)
                stg[i] = *(const u32x4*)(W + (size_t)sn[i] * K + kn + sk[i]);
        }
        short8 avc0 = *(const short8*)&Atile[arow * LDA + (c << 6) + quad * 8];
        short8 avc1 = *(const short8*)&Atile[arow * LDA + (c << 6) + 32 + quad * 8];
        #pragma unroll
        for (int nt = 0; nt < 10; ++nt) {
            short8 bv0 = *(const short8*)&WtL[pb][(nt * 16 + l15) * LDW + quad * 8];
            acc[nt] = __builtin_amdgcn_mfma_f32_16x16x32_bf16(avc0, bv0, acc[nt], 0, 0, 0);
            short8 bv1 = *(const short8*)&WtL[pb][(nt * 16 + l15) * LDW + 32 + quad * 8];
            acc[nt] = __builtin_amdgcn_mfma_f32_16x16x32_bf16(avc1, bv1, acc[nt], 0, 0, 0);
        }
        if (more) {
            #pragma unroll
            for (int i = 0; i < 5; ++i)
                *(u32x4*)&WtL[pb ^ 1][sn[i] * LDW + sk[i]] = stg[i];
        }
        __syncthreads();
    }

    // ---- fused layer3 dot epilogue ----
    float part[4] = {0.f, 0.f, 0.f, 0.f};
    #pragma unroll
    for (int nt = 0; nt < 10; ++nt) {
        int col = nt * 16 + l15;
        float bv_ = (col < HID) ? bs2[col] : 0.f;
        float vv = (col < HID) ? Ws3[col] : 0.f;
        #pragma unroll
        for (int r = 0; r < 4; ++r)
            part[r] += fmaxf(acc[nt][r] + bv_, 0.f) * vv;
    }
    const int rbase = blockIdx.x * 64 + wid * 16 + quad * 4;
    #pragma unroll
    for (int r = 0; r < 4; ++r) {
        float p = part[r];
        #pragma unroll
        for (int off = 1; off < 16; off <<= 1) p += __shfl_xor(p, off);
        if (l15 == 0) out[rbase + r] = p + bs3[0];
    }
}

extern "C" void kernel_launch(void* const* d_in, const int* in_sizes, int n_in,
                              void* d_out, int out_size, void* d_ws, size_t ws_size,
                              hipStream_t stream) {
    const float* states = (const float*)d_in[0];
    const float* embeds = (const float*)d_in[1];
    const int* span_starts = (const int*)d_in[2];
    const int* span_lengths = (const int*)d_in[3];
    const float* Wa1 = (const float*)d_in[4];
    const float* ba1 = (const float*)d_in[5];
    const float* Wa2 = (const float*)d_in[6];
    const float* ba2 = (const float*)d_in[7];
    const float* Wa3 = (const float*)d_in[8];
    const float* ba3 = (const float*)d_in[9];
    const float* width_table = (const float*)d_in[10];
    const float* Ws1 = (const float*)d_in[11];
    const float* bs1 = (const float*)d_in[12];
    const float* Ws2 = (const float*)d_in[13];
    const float* bs2 = (const float*)d_in[14];
    const float* Ws3 = (const float*)d_in[15];
    const float* bs3 = (const float*)d_in[16];
    float* out = (float*)d_out;

    // ---- workspace layout ----
    char* w = (char*)d_ws;
    unsigned short* WtA  = (unsigned short*)w;  w += 480 * 1024 * 2;
    unsigned short* WtE  = (unsigned short*)w;  w += 160 * 512 * 2;
    unsigned short* Wa2t = (unsigned short*)w;  w += 160 * 192 * 2;
    unsigned short* Ws2t = (unsigned short*)w;  w += 160 * 192 * 2;
    float* PW    = (float*)w;                   w += 5632;
    float* attns = (float*)w;                   w += 8192 * 4;
    unsigned short* Sbf = (unsigned short*)w;   w += (size_t)T_TOK * A_DIM * 2;
    unsigned short* Ebf = (unsigned short*)w;   w += (size_t)T_TOK * E_DIM * 2;
    unsigned short* Psh = (unsigned short*)w;   w += (size_t)T_TOK * 160 * 2;   // bf16
    unsigned short* Peh = (unsigned short*)w;   w += (size_t)T_TOK * 160 * 2;   // bf16
    unsigned short* Pmh = (unsigned short*)w;   w += (size_t)T_TOK * 160 * 2;   // bf16
    unsigned short* H1A = (unsigned short*)w;   w += (size_t)T_TOK * 192 * 2;   // bf16
    // No memsets: pad cols (0xAA poison = finite bf16) multiply zeroed W rows.

    // ---- fused prep: cast + weight transposes + width proj ----
    PrepTab pt;
    pt.s = states; pt.e = embeds; pt.sd = Sbf; pt.ed = Ebf;
    pt.g[0] = { Wa1,              WtA,              1024, 1024, (160*1024 + 255)/256 };
    pt.g[1] = { Ws1,              WtA + 160*1024,   1024, 1024, (160*1024 + 255)/256 };
    pt.g[2] = { Ws1 + 1024*150,   WtA + 320*1024,   1024, 1024, (160*1024 + 255)/256 };
    pt.g[3] = { Ws1 + 2048*150,   WtE,               512,  512, (160*512  + 255)/256 };
    pt.g[4] = { Wa2,              Wa2t,              150,  192, (160*192  + 255)/256 };
    pt.g[5] = { Ws2,              Ws2t,              150,  192, (160*192  + 255)/256 };
    pt.wt = width_table; pt.Ws1w = Ws1 + 2560*150; pt.PW = PW;
    int wblk = 0; for (int i = 0; i < 6; ++i) wblk += pt.g[i].nblk;
    prep_kernel<<<NCAST + wblk + 9, 256, 0, stream>>>(pt);

    GG z = {};

    // ---- fused GEMM1+2: 4 groups, 512 blocks (3 blocks/CU) ----
    GTab t1; t1.ng = 4;
    t1.g[0] = z; t1.g[0].A = Sbf; t1.g[0].lda = 1024; t1.g[0].W = WtA;            t1.g[0].K = 1024;
    t1.g[0].nrb = 128; t1.g[0].outh = H1A; t1.g[0].ldo = 192; t1.g[0].bias = ba1; t1.g[0].relu = 1;
    t1.g[1] = z; t1.g[1].A = Sbf; t1.g[1].lda = 1024; t1.g[1].W = WtA + 160*1024; t1.g[1].K = 1024;
    t1.g[1].nrb = 128; t1.g[1].outh = Psh; t1.g[1].ldo = 160;
    t1.g[2] = z; t1.g[2].A = Sbf; t1.g[2].lda = 1024; t1.g[2].W = WtA + 320*1024; t1.g[2].K = 1024;
    t1.g[2].nrb = 128; t1.g[2].outh = Peh; t1.g[2].ldo = 160;
    t1.g[3] = z; t1.g[3].A = Ebf; t1.g[3].lda = 512;  t1.g[3].W = WtE;            t1.g[3].K = 512;
    t1.g[3].nrb = 128; t1.g[3].outh = Pmh; t1.g[3].ldo = 160;
    gemm_fused<1><<<512, 256, 0, stream>>>(t1);

    // ---- attn layer2 + fused layer3 dot -> attns ----
    GTab t2; t2.ng = 1;
    t2.g[0] = z; t2.g[0].A = H1A; t2.g[0].lda = 192; t2.g[0].W = Wa2t; t2.g[0].K = 192;
    t2.g[0].nrb = 128; t2.g[0].bias = ba2; t2.g[0].dotv = Wa3; t2.g[0].dotb = ba3; t2.g[0].dotout = attns;
    gemm_fused<2><<<128, 256, 0, stream>>>(t2);

    // ---- merged span layer1 + layer2 GEMM + layer3 dot -> out ----
    span_gemm_kernel<<<512, 256, 0, stream>>>(attns, span_starts, span_lengths,
                                              Psh, Peh, Pmh, PW, bs1,
                                              Ws2t, bs2, Ws3, bs3, out);
}

// Round 12
// 181.341 us; speedup vs baseline: 1.0503x; 1.0503x over previous
//
#include <hip/hip_runtime.h>
#include <math.h>

#define T_TOK 8192
#define A_DIM 1024
#define E_DIM 512
#define S_SPAN 32768
#define HID 150

typedef __attribute__((ext_vector_type(8))) short short8;
typedef __attribute__((ext_vector_type(4))) float f32x4;
typedef __attribute__((ext_vector_type(4))) unsigned int u32x4;
typedef __attribute__((ext_vector_type(4))) unsigned short u16x4;

__device__ __forceinline__ unsigned short f2bf(float f) {
    unsigned int u = __builtin_bit_cast(unsigned int, f);
    u += 0x7FFFu + ((u >> 16) & 1u);          // RNE
    return (unsigned short)(u >> 16);
}
__device__ __forceinline__ float bf2f(unsigned int h16) {
    unsigned int u = h16 << 16;
    return __builtin_bit_cast(float, u);
}

// ---------------------------------------------------------------------------
// fused prep: input cast (fp32->bf16) + 6 weight transposes + width proj
// ---------------------------------------------------------------------------
#define NS4 (T_TOK * A_DIM / 4)   // 2097152
#define NE4 (T_TOK * E_DIM / 4)   // 1048576
#define NCAST ((NS4 + NE4) / 256) // 12288 exactly

struct WConv { const float* src; unsigned short* dst; int K0; int Kpad; int nblk; };
struct PrepTab {
    const float* s; const float* e; unsigned short* sd; unsigned short* ed;
    WConv g[6];
    const float* wt; const float* Ws1w; float* PW;
};

__global__ __launch_bounds__(256) void prep_kernel(PrepTab tab) {
    int b = blockIdx.x;
    if (b < NCAST) {
        int idx = b * 256 + threadIdx.x;
        const float* src; unsigned short* dst;
        if (idx < NS4) { src = tab.s; dst = tab.sd; }
        else { idx -= NS4; src = tab.e; dst = tab.ed; }
        f32x4 v = *(const f32x4*)(src + (size_t)idx * 4);
        u16x4 o;
        o.x = f2bf(v.x); o.y = f2bf(v.y); o.z = f2bf(v.z); o.w = f2bf(v.w);
        *(u16x4*)(dst + (size_t)idx * 4) = o;
        return;
    }
    b -= NCAST;
    #pragma unroll
    for (int gi = 0; gi < 6; ++gi) {
        if (b < tab.g[gi].nblk) {
            int idx = b * 256 + threadIdx.x;               // idx = k*160 + j
            int Kpad = tab.g[gi].Kpad;
            if (idx < Kpad * 160) {
                int k = idx / 160, j = idx - k * 160;
                float v = (j < HID && k < tab.g[gi].K0)
                          ? tab.g[gi].src[(size_t)k * HID + j] : 0.f;   // coalesced read
                tab.g[gi].dst[(size_t)j * Kpad + k] = f2bf(v);          // scattered write
            }
            return;
        }
        b -= tab.g[gi].nblk;
    }
    // width projection: 9 blocks
    int j = threadIdx.x;
    if (j < HID) {
        float acc = 0.f;
        for (int k = 0; k < 20; ++k)
            acc = fmaf(tab.wt[b * 20 + k], tab.Ws1w[k * HID + j], acc);
        tab.PW[b * HID + j] = acc;
    }
}

// ---------------------------------------------------------------------------
// unified MFMA GEMM: dbuf BK=64, LDW=72 (46 KB, 3 blocks/CU).
// NEW 2x2 wave tiling: wave (g = wid>>1, h = wid&1) covers rows g*32..+31
// (2 m-frags) x cols h*80..+79 (5 n-tiles). Per chunk per wave:
// 10 ds_read_b128 vs 20 MFMAs (was 20:20) -> halves LDS-read pressure.
// ---------------------------------------------------------------------------
struct GG {
    const unsigned short* A; int lda;
    const unsigned short* W; int K; int nrb;
    unsigned short* outh; int ldo;
    const float* bias; int relu;
    const float* dotv; const float* dotb; float* dotout;
};
struct GTab { GG g[4]; int ng; };

template <int TAG>
__global__ __launch_bounds__(256) void gemm_fused(GTab tab) {
    constexpr int LDW = 72;
    __shared__ unsigned short WtL[2][160 * LDW];
    __shared__ float dsum[64];

    int b = blockIdx.x;
    int gi = 0;
    while (gi < tab.ng - 1 && b >= tab.g[gi].nrb) { b -= tab.g[gi].nrb; ++gi; }
    const GG G = tab.g[gi];

    const int tid = threadIdx.x;
    const int wid = tid >> 6;
    const int lane = tid & 63;
    const int l15 = lane & 15;
    const int quad = lane >> 4;
    const int g = wid >> 1;       // row half
    const int h = wid & 1;        // col half
    const int row0 = b * 64 + g * 32 + l15;
    const int K = G.K;
    const int nch = K >> 6;
    const unsigned short* Arow0 = G.A + (size_t)row0 * G.lda;
    const unsigned short* Arow1 = G.A + (size_t)(row0 + 16) * G.lda;

    // staging registers for W chunk: 1280 16B units / 256 thr = 5 each
    u32x4 stg[5];
    int sn[5], sk[5];
    #pragma unroll
    for (int i = 0; i < 5; ++i) { int u = tid + i * 256; sn[i] = u >> 3; sk[i] = (u & 7) * 8; }

    f32x4 acc[2][5];
    #pragma unroll
    for (int mt = 0; mt < 2; ++mt)
        #pragma unroll
        for (int nt = 0; nt < 5; ++nt) acc[mt][nt] = (f32x4){0.f, 0.f, 0.f, 0.f};

    #pragma unroll
    for (int i = 0; i < 5; ++i)
        stg[i] = *(const u32x4*)(G.W + (size_t)sn[i] * K + sk[i]);
    short8 a00 = *(const short8*)(Arow0 + quad * 8);
    short8 a01 = *(const short8*)(Arow0 + 32 + quad * 8);
    short8 a10 = *(const short8*)(Arow1 + quad * 8);
    short8 a11 = *(const short8*)(Arow1 + 32 + quad * 8);
    #pragma unroll
    for (int i = 0; i < 5; ++i)
        *(u32x4*)&WtL[0][sn[i] * LDW + sk[i]] = stg[i];
    __syncthreads();

    for (int c = 0; c < nch; ++c) {
        const int pb = c & 1;
        short8 n00, n01, n10, n11;
        const bool more = (c + 1 < nch);
        if (more) {
            const int kn = (c + 1) << 6;
            #pragma unroll
            for (int i = 0; i < 5; ++i)
                stg[i] = *(const u32x4*)(G.W + (size_t)sn[i] * K + kn + sk[i]);
            n00 = *(const short8*)(Arow0 + kn + quad * 8);
            n01 = *(const short8*)(Arow0 + kn + 32 + quad * 8);
            n10 = *(const short8*)(Arow1 + kn + quad * 8);
            n11 = *(const short8*)(Arow1 + kn + 32 + quad * 8);
        }
        #pragma unroll
        for (int nt = 0; nt < 5; ++nt) {
            const int wrow = (h * 80 + nt * 16 + l15) * LDW;
            short8 bv0 = *(const short8*)&WtL[pb][wrow + quad * 8];
            acc[0][nt] = __builtin_amdgcn_mfma_f32_16x16x32_bf16(a00, bv0, acc[0][nt], 0, 0, 0);
            acc[1][nt] = __builtin_amdgcn_mfma_f32_16x16x32_bf16(a10, bv0, acc[1][nt], 0, 0, 0);
            short8 bv1 = *(const short8*)&WtL[pb][wrow + 32 + quad * 8];
            acc[0][nt] = __builtin_amdgcn_mfma_f32_16x16x32_bf16(a01, bv1, acc[0][nt], 0, 0, 0);
            acc[1][nt] = __builtin_amdgcn_mfma_f32_16x16x32_bf16(a11, bv1, acc[1][nt], 0, 0, 0);
        }
        if (more) {
            #pragma unroll
            for (int i = 0; i < 5; ++i)
                *(u32x4*)&WtL[pb ^ 1][sn[i] * LDW + sk[i]] = stg[i];
            a00 = n00; a01 = n01; a10 = n10; a11 = n11;
        }
        __syncthreads();
    }

    if (G.dotout) {
        // partial dot over this wave's 80 cols; combine col-halves via LDS.
        float part[2][4];
        #pragma unroll
        for (int mt = 0; mt < 2; ++mt)
            #pragma unroll
            for (int r = 0; r < 4; ++r) part[mt][r] = 0.f;
        #pragma unroll
        for (int nt = 0; nt < 5; ++nt) {
            int col = h * 80 + nt * 16 + l15;
            float bv_ = (col < HID) ? G.bias[col] : 0.f;
            float vv = (col < HID) ? G.dotv[col] : 0.f;
            #pragma unroll
            for (int mt = 0; mt < 2; ++mt)
                #pragma unroll
                for (int r = 0; r < 4; ++r)
                    part[mt][r] += fmaxf(acc[mt][nt][r] + bv_, 0.f) * vv;
        }
        #pragma unroll
        for (int mt = 0; mt < 2; ++mt)
            #pragma unroll
            for (int r = 0; r < 4; ++r) {
                #pragma unroll
                for (int off = 1; off < 16; off <<= 1)
                    part[mt][r] += __shfl_xor(part[mt][r], off);
            }
        if (h == 0 && l15 == 0) {
            #pragma unroll
            for (int mt = 0; mt < 2; ++mt)
                #pragma unroll
                for (int r = 0; r < 4; ++r)
                    dsum[g * 32 + mt * 16 + quad * 4 + r] = part[mt][r];
        }
        __syncthreads();
        if (h == 1 && l15 == 0) {
            #pragma unroll
            for (int mt = 0; mt < 2; ++mt)
                #pragma unroll
                for (int r = 0; r < 4; ++r) {
                    int lr = g * 32 + mt * 16 + quad * 4 + r;
                    G.dotout[b * 64 + lr] = dsum[lr] + part[mt][r] + G.dotb[0];
                }
        }
    } else {
        #pragma unroll
        for (int nt = 0; nt < 5; ++nt) {
            int col = h * 80 + nt * 16 + l15;
            float bv_ = (G.bias != nullptr && col < HID) ? G.bias[col] : 0.f;
            #pragma unroll
            for (int mt = 0; mt < 2; ++mt)
                #pragma unroll
                for (int r = 0; r < 4; ++r) {
                    int row = b * 64 + g * 32 + mt * 16 + quad * 4 + r;
                    float v = acc[mt][nt][r] + bv_;
                    if (G.relu) v = fmaxf(v, 0.f);
                    G.outh[(size_t)row * G.ldo + col] = f2bf(v);
                }
        }
    }
}

// ---------------------------------------------------------------------------
// span layer-1: one wave per span; bf16 P gathers via packed u32 pairs.
// writes SH1 bf16 [S x 192] cols 0..149.
// ---------------------------------------------------------------------------
__global__ __launch_bounds__(256) void span_l1_kernel(const float* __restrict__ attns,
                                                      const int* __restrict__ starts,
                                                      const int* __restrict__ lens,
                                                      const unsigned short* __restrict__ Ps,
                                                      const unsigned short* __restrict__ Pe,
                                                      const unsigned short* __restrict__ Pm,
                                                      const float* __restrict__ PW,
                                                      const float* __restrict__ bs1,
                                                      unsigned short* __restrict__ SH1) {
    const int wid = threadIdx.x >> 6, lane = threadIdx.x & 63;
    const int s = blockIdx.x * 4 + wid;
    const int start = starts[s];
    const int len = lens[s];

    const int iv = min(start + lane, T_TOK - 1);
    float a = (lane <= len) ? attns[iv] : -INFINITY;
    float m = a;
    #pragma unroll
    for (int off = 32; off; off >>= 1) m = fmaxf(m, __shfl_xor(m, off));
    float e = (lane <= len) ? __expf(a - m) : 0.f;
    float ssum = e;
    #pragma unroll
    for (int off = 32; off; off >>= 1) ssum += __shfl_xor(ssum, off);
    float wv = e / ssum;

    float wl[10]; int il[10];
    #pragma unroll
    for (int l = 0; l < 10; ++l) { wl[l] = __shfl(wv, l); il[l] = __shfl(iv, l); }

    const int end = start + len;
    const int width = len + 1;
    const int bucket = (width >= 1) + (width >= 2) + (width >= 3) + (width >= 4) +
                       (width >= 8) + (width >= 16) + (width >= 32) + (width >= 64);

    const unsigned short* ps = Ps + (size_t)start * 160;
    const unsigned short* pe = Pe + (size_t)end * 160;
    const float* pw = PW + bucket * HID;

    for (int p = lane; p < 75; p += 64) {
        const int j = 2 * p;
        unsigned int u0 = *(const unsigned int*)(ps + j);
        unsigned int u1 = *(const unsigned int*)(pe + j);
        float a0 = bs1[j]     + bf2f(u0 & 0xffff) + bf2f(u1 & 0xffff) + pw[j];
        float a1 = bs1[j + 1] + bf2f(u0 >> 16)    + bf2f(u1 >> 16)    + pw[j + 1];
        #pragma unroll
        for (int l = 0; l < 10; ++l) {
            unsigned int um = *(const unsigned int*)(Pm + (size_t)il[l] * 160 + j);
            a0 = fmaf(wl[l], bf2f(um & 0xffff), a0);
            a1 = fmaf(wl[l], bf2f(um >> 16), a1);
        }
        unsigned int packed = (unsigned int)f2bf(fmaxf(a0, 0.f)) |
                              ((unsigned int)f2bf(fmaxf(a1, 0.f)) << 16);
        *(unsigned int*)(SH1 + (size_t)s * 192 + j) = packed;
    }
}

extern "C" void kernel_launch(void* const* d_in, const int* in_sizes, int n_in,
                              void* d_out, int out_size, void* d_ws, size_t ws_size,
                              hipStream_t stream) {
    const float* states = (const float*)d_in[0];
    const float* embeds = (const float*)d_in[1];
    const int* span_starts = (const int*)d_in[2];
    const int* span_lengths = (const int*)d_in[3];
    const float* Wa1 = (const float*)d_in[4];
    const float* ba1 = (const float*)d_in[5];
    const float* Wa2 = (const float*)d_in[6];
    const float* ba2 = (const float*)d_in[7];
    const float* Wa3 = (const float*)d_in[8];
    const float* ba3 = (const float*)d_in[9];
    const float* width_table = (const float*)d_in[10];
    const float* Ws1 = (const float*)d_in[11];
    const float* bs1 = (const float*)d_in[12];
    const float* Ws2 = (const float*)d_in[13];
    const float* bs2 = (const float*)d_in[14];
    const float* Ws3 = (const float*)d_in[15];
    const float* bs3 = (const float*)d_in[16];
    float* out = (float*)d_out;

    // ---- workspace layout ----
    char* w = (char*)d_ws;
    unsigned short* WtA  = (unsigned short*)w;  w += 480 * 1024 * 2;
    unsigned short* WtE  = (unsigned short*)w;  w += 160 * 512 * 2;
    unsigned short* Wa2t = (unsigned short*)w;  w += 160 * 192 * 2;
    unsigned short* Ws2t = (unsigned short*)w;  w += 160 * 192 * 2;
    float* PW    = (float*)w;                   w += 5632;
    float* attns = (float*)w;                   w += 8192 * 4;
    unsigned short* Sbf = (unsigned short*)w;   w += (size_t)T_TOK * A_DIM * 2;
    unsigned short* Ebf = (unsigned short*)w;   w += (size_t)T_TOK * E_DIM * 2;
    unsigned short* Psh = (unsigned short*)w;   w += (size_t)T_TOK * 160 * 2;   // bf16
    unsigned short* Peh = (unsigned short*)w;   w += (size_t)T_TOK * 160 * 2;   // bf16
    unsigned short* Pmh = (unsigned short*)w;   w += (size_t)T_TOK * 160 * 2;   // bf16
    unsigned short* H1A = (unsigned short*)w;   w += (size_t)T_TOK * 192 * 2;   // bf16
    unsigned short* SH1 = (unsigned short*)w;   w += (size_t)S_SPAN * 192 * 2;  // bf16
    // No memsets: pad cols (0xAA poison = finite bf16) multiply zeroed W rows.

    // ---- fused prep: cast + weight transposes + width proj ----
    PrepTab pt;
    pt.s = states; pt.e = embeds; pt.sd = Sbf; pt.ed = Ebf;
    pt.g[0] = { Wa1,              WtA,              1024, 1024, (160*1024 + 255)/256 };
    pt.g[1] = { Ws1,              WtA + 160*1024,   1024, 1024, (160*1024 + 255)/256 };
    pt.g[2] = { Ws1 + 1024*150,   WtA + 320*1024,   1024, 1024, (160*1024 + 255)/256 };
    pt.g[3] = { Ws1 + 2048*150,   WtE,               512,  512, (160*512  + 255)/256 };
    pt.g[4] = { Wa2,              Wa2t,              150,  192, (160*192  + 255)/256 };
    pt.g[5] = { Ws2,              Ws2t,              150,  192, (160*192  + 255)/256 };
    pt.wt = width_table; pt.Ws1w = Ws1 + 2560*150; pt.PW = PW;
    int wblk = 0; for (int i = 0; i < 6; ++i) wblk += pt.g[i].nblk;
    prep_kernel<<<NCAST + wblk + 9, 256, 0, stream>>>(pt);

    GG z = {};

    // ---- fused GEMM1+2: 4 groups, 512 blocks (3 blocks/CU) ----
    GTab t1; t1.ng = 4;
    t1.g[0] = z; t1.g[0].A = Sbf; t1.g[0].lda = 1024; t1.g[0].W = WtA;            t1.g[0].K = 1024;
    t1.g[0].nrb = 128; t1.g[0].outh = H1A; t1.g[0].ldo = 192; t1.g[0].bias = ba1; t1.g[0].relu = 1;
    t1.g[1] = z; t1.g[1].A = Sbf; t1.g[1].lda = 1024; t1.g[1].W = WtA + 160*1024; t1.g[1].K = 1024;
    t1.g[1].nrb = 128; t1.g[1].outh = Psh; t1.g[1].ldo = 160;
    t1.g[2] = z; t1.g[2].A = Sbf; t1.g[2].lda = 1024; t1.g[2].W = WtA + 320*1024; t1.g[2].K = 1024;
    t1.g[2].nrb = 128; t1.g[2].outh = Peh; t1.g[2].ldo = 160;
    t1.g[3] = z; t1.g[3].A = Ebf; t1.g[3].lda = 512;  t1.g[3].W = WtE;            t1.g[3].K = 512;
    t1.g[3].nrb = 128; t1.g[3].outh = Pmh; t1.g[3].ldo = 160;
    gemm_fused<1><<<512, 256, 0, stream>>>(t1);

    // ---- attn layer2 + fused layer3 dot -> attns ----
    GTab t2; t2.ng = 1;
    t2.g[0] = z; t2.g[0].A = H1A; t2.g[0].lda = 192; t2.g[0].W = Wa2t; t2.g[0].K = 192;
    t2.g[0].nrb = 128; t2.g[0].bias = ba2; t2.g[0].dotv = Wa3; t2.g[0].dotb = ba3; t2.g[0].dotout = attns;
    gemm_fused<2><<<128, 256, 0, stream>>>(t2);

    // ---- span layer1 -> SH1 (bf16) ----
    span_l1_kernel<<<S_SPAN / 4, 256, 0, stream>>>(attns, span_starts, span_lengths,
                                                   Psh, Peh, Pmh, PW, bs1, SH1);

    // ---- span layer2 + fused layer3 dot -> out ----
    GTab t3; t3.ng = 1;
    t3.g[0] = z; t3.g[0].A = SH1; t3.g[0].lda = 192; t3.g[0].W = Ws2t; t3.g[0].K = 192;
    t3.g[0].nrb = 512; t3.g[0].bias = bs2; t3.g[0].dotv = Ws3; t3.g[0].dotb = bs3; t3.g[0].dotout = out;
    gemm_fused<3><<<512, 256, 0, stream>>>(t3);
}

// Round 13
// 173.028 us; speedup vs baseline: 1.1008x; 1.0480x over previous
//
#include <hip/hip_runtime.h>
#include <math.h>

#define T_TOK 8192
#define A_DIM 1024
#define E_DIM 512
#define S_SPAN 32768
#define HID 150

typedef __attribute__((ext_vector_type(8))) short short8;
typedef __attribute__((ext_vector_type(4))) float f32x4;
typedef __attribute__((ext_vector_type(4))) unsigned int u32x4;

__device__ __forceinline__ unsigned short f2bf(float f) {
    unsigned int u = __builtin_bit_cast(unsigned int, f);
    u += 0x7FFFu + ((u >> 16) & 1u);          // RNE
    return (unsigned short)(u >> 16);
}
__device__ __forceinline__ float bf2f(unsigned int h16) {
    unsigned int u = h16 << 16;
    return __builtin_bit_cast(float, u);
}
__device__ __forceinline__ short8 cast8(f32x4 a, f32x4 b) {
    short8 r;
    r[0] = (short)f2bf(a.x); r[1] = (short)f2bf(a.y);
    r[2] = (short)f2bf(a.z); r[3] = (short)f2bf(a.w);
    r[4] = (short)f2bf(b.x); r[5] = (short)f2bf(b.y);
    r[6] = (short)f2bf(b.z); r[7] = (short)f2bf(b.w);
    return r;
}

// ---------------------------------------------------------------------------
// prep: 6 weight transposes + width projection (71 blocks; no input cast)
// ---------------------------------------------------------------------------
struct WConv { const float* src; unsigned short* dst; int K0; int Kpad; int nblk; };
struct PrepTab {
    WConv g[6];
    const float* wt; const float* Ws1w; float* PW;
};

__global__ __launch_bounds__(256) void prep_kernel(PrepTab tab) {
    int b = blockIdx.x;
    #pragma unroll
    for (int gi = 0; gi < 6; ++gi) {
        if (b < tab.g[gi].nblk) {
            int idx = b * 256 + threadIdx.x;               // idx = k*160 + j
            int Kpad = tab.g[gi].Kpad;
            if (idx < Kpad * 160) {
                int k = idx / 160, j = idx - k * 160;
                float v = (j < HID && k < tab.g[gi].K0)
                          ? tab.g[gi].src[(size_t)k * HID + j] : 0.f;   // coalesced read
                tab.g[gi].dst[(size_t)j * Kpad + k] = f2bf(v);          // scattered write
            }
            return;
        }
        b -= tab.g[gi].nblk;
    }
    // width projection: 9 blocks
    int j = threadIdx.x;
    if (j < HID) {
        float acc = 0.f;
        for (int k = 0; k < 20; ++k)
            acc = fmaf(tab.wt[b * 20 + k], tab.Ws1w[k * HID + j], acc);
        tab.PW[b * HID + j] = acc;
    }
}

// ---------------------------------------------------------------------------
// unified MFMA GEMM (R10 structure): dbuf BK=64, LDW=72 (46 KB, 3 blocks/CU).
// AF32: A is fp32, cast to bf16 in-register AFTER the MFMA block (same RNE
// rounding as the old pre-cast pass -> bit-identical results).
// ---------------------------------------------------------------------------
struct GG {
    const void* A; int lda;
    const unsigned short* W; int K; int nrb;
    unsigned short* outh; int ldo;
    const float* bias; int relu;
    const float* dotv; const float* dotb; float* dotout;
};
struct GTab { GG g[4]; int ng; };

template <int TAG, bool AF32>
__global__ __launch_bounds__(256) void gemm_fused(GTab tab) {
    constexpr int LDW = 72;
    __shared__ unsigned short WtL[2][160 * LDW];

    int b = blockIdx.x;
    int gi = 0;
    while (gi < tab.ng - 1 && b >= tab.g[gi].nrb) { b -= tab.g[gi].nrb; ++gi; }
    const GG G = tab.g[gi];

    const int tid = threadIdx.x;
    const int wid = tid >> 6;
    const int lane = tid & 63;
    const int l15 = lane & 15;
    const int quad = lane >> 4;
    const int row0 = b * 64 + wid * 16 + l15;
    const int K = G.K;
    const int nch = K >> 6;
    const float* Af = (const float*)G.A + (size_t)row0 * G.lda;
    const unsigned short* Ah = (const unsigned short*)G.A + (size_t)row0 * G.lda;

    // staging registers for W chunk: 1280 16B units / 256 thr = 5 each
    u32x4 stg[5];
    int sn[5], sk[5];
    #pragma unroll
    for (int i = 0; i < 5; ++i) { int u = tid + i * 256; sn[i] = u >> 3; sk[i] = (u & 7) * 8; }

    f32x4 acc[10];
    #pragma unroll
    for (int nt = 0; nt < 10; ++nt) acc[nt] = (f32x4){0.f, 0.f, 0.f, 0.f};

    #pragma unroll
    for (int i = 0; i < 5; ++i)
        stg[i] = *(const u32x4*)(G.W + (size_t)sn[i] * K + sk[i]);
    short8 avc0, avc1;
    if (AF32) {
        f32x4 f0 = *(const f32x4*)(Af + quad * 8);
        f32x4 f1 = *(const f32x4*)(Af + quad * 8 + 4);
        f32x4 f2 = *(const f32x4*)(Af + 32 + quad * 8);
        f32x4 f3 = *(const f32x4*)(Af + 32 + quad * 8 + 4);
        avc0 = cast8(f0, f1);
        avc1 = cast8(f2, f3);
    } else {
        avc0 = *(const short8*)(Ah + quad * 8);
        avc1 = *(const short8*)(Ah + 32 + quad * 8);
    }
    #pragma unroll
    for (int i = 0; i < 5; ++i)
        *(u32x4*)&WtL[0][sn[i] * LDW + sk[i]] = stg[i];
    __syncthreads();

    for (int c = 0; c < nch; ++c) {
        const int pb = c & 1;
        short8 avn0, avn1;
        f32x4 fn0, fn1, fn2, fn3;
        const bool more = (c + 1 < nch);
        if (more) {
            const int kn = (c + 1) << 6;
            #pragma unroll
            for (int i = 0; i < 5; ++i)
                stg[i] = *(const u32x4*)(G.W + (size_t)sn[i] * K + kn + sk[i]);
            if (AF32) {
                fn0 = *(const f32x4*)(Af + kn + quad * 8);
                fn1 = *(const f32x4*)(Af + kn + quad * 8 + 4);
                fn2 = *(const f32x4*)(Af + kn + 32 + quad * 8);
                fn3 = *(const f32x4*)(Af + kn + 32 + quad * 8 + 4);
            } else {
                avn0 = *(const short8*)(Ah + kn + quad * 8);
                avn1 = *(const short8*)(Ah + kn + 32 + quad * 8);
            }
        }
        #pragma unroll
        for (int nt = 0; nt < 10; ++nt) {
            short8 bv0 = *(const short8*)&WtL[pb][(nt * 16 + l15) * LDW + quad * 8];
            acc[nt] = __builtin_amdgcn_mfma_f32_16x16x32_bf16(avc0, bv0, acc[nt], 0, 0, 0);
            short8 bv1 = *(const short8*)&WtL[pb][(nt * 16 + l15) * LDW + 32 + quad * 8];
            acc[nt] = __builtin_amdgcn_mfma_f32_16x16x32_bf16(avc1, bv1, acc[nt], 0, 0, 0);
        }
        if (more) {
            #pragma unroll
            for (int i = 0; i < 5; ++i)
                *(u32x4*)&WtL[pb ^ 1][sn[i] * LDW + sk[i]] = stg[i];
            if (AF32) {
                avc0 = cast8(fn0, fn1);
                avc1 = cast8(fn2, fn3);
            } else {
                avc0 = avn0; avc1 = avn1;
            }
        }
        __syncthreads();
    }

    const int rbase = b * 64 + wid * 16 + quad * 4;
    if (G.dotout) {
        float part[4] = {0.f, 0.f, 0.f, 0.f};
        #pragma unroll
        for (int nt = 0; nt < 10; ++nt) {
            int col = nt * 16 + l15;
            float bv_ = (col < HID) ? G.bias[col] : 0.f;
            float vv = (col < HID) ? G.dotv[col] : 0.f;
            #pragma unroll
            for (int r = 0; r < 4; ++r)
                part[r] += fmaxf(acc[nt][r] + bv_, 0.f) * vv;
        }
        #pragma unroll
        for (int r = 0; r < 4; ++r) {
            float p = part[r];
            #pragma unroll
            for (int off = 1; off < 16; off <<= 1) p += __shfl_xor(p, off);
            if (l15 == 0) G.dotout[rbase + r] = p + G.dotb[0];
        }
    } else {
        #pragma unroll
        for (int nt = 0; nt < 10; ++nt) {
            int col = nt * 16 + l15;
            float bv_ = (G.bias != nullptr && col < HID) ? G.bias[col] : 0.f;
            #pragma unroll
            for (int r = 0; r < 4; ++r) {
                int row = rbase + r;
                float v = acc[nt][r] + bv_;
                if (G.relu) v = fmaxf(v, 0.f);
                G.outh[(size_t)row * G.ldo + col] = f2bf(v);
            }
        }
    }
}

// ---------------------------------------------------------------------------
// span layer-1: one wave per span; bf16 P gathers via packed u32 pairs.
// writes SH1 bf16 [S x 192] cols 0..149.
// ---------------------------------------------------------------------------
__global__ __launch_bounds__(256) void span_l1_kernel(const float* __restrict__ attns,
                                                      const int* __restrict__ starts,
                                                      const int* __restrict__ lens,
                                                      const unsigned short* __restrict__ Ps,
                                                      const unsigned short* __restrict__ Pe,
                                                      const unsigned short* __restrict__ Pm,
                                                      const float* __restrict__ PW,
                                                      const float* __restrict__ bs1,
                                                      unsigned short* __restrict__ SH1) {
    const int wid = threadIdx.x >> 6, lane = threadIdx.x & 63;
    const int s = blockIdx.x * 4 + wid;
    const int start = starts[s];
    const int len = lens[s];

    const int iv = min(start + lane, T_TOK - 1);
    float a = (lane <= len) ? attns[iv] : -INFINITY;
    float m = a;
    #pragma unroll
    for (int off = 32; off; off >>= 1) m = fmaxf(m, __shfl_xor(m, off));
    float e = (lane <= len) ? __expf(a - m) : 0.f;
    float ssum = e;
    #pragma unroll
    for (int off = 32; off; off >>= 1) ssum += __shfl_xor(ssum, off);
    float wv = e / ssum;

    float wl[10]; int il[10];
    #pragma unroll
    for (int l = 0; l < 10; ++l) { wl[l] = __shfl(wv, l); il[l] = __shfl(iv, l); }

    const int end = start + len;
    const int width = len + 1;
    const int bucket = (width >= 1) + (width >= 2) + (width >= 3) + (width >= 4) +
                       (width >= 8) + (width >= 16) + (width >= 32) + (width >= 64);

    const unsigned short* ps = Ps + (size_t)start * 160;
    const unsigned short* pe = Pe + (size_t)end * 160;
    const float* pw = PW + bucket * HID;

    for (int p = lane; p < 75; p += 64) {
        const int j = 2 * p;
        unsigned int u0 = *(const unsigned int*)(ps + j);
        unsigned int u1 = *(const unsigned int*)(pe + j);
        float a0 = bs1[j]     + bf2f(u0 & 0xffff) + bf2f(u1 & 0xffff) + pw[j];
        float a1 = bs1[j + 1] + bf2f(u0 >> 16)    + bf2f(u1 >> 16)    + pw[j + 1];
        #pragma unroll
        for (int l = 0; l < 10; ++l) {
            unsigned int um = *(const unsigned int*)(Pm + (size_t)il[l] * 160 + j);
            a0 = fmaf(wl[l], bf2f(um & 0xffff), a0);
            a1 = fmaf(wl[l], bf2f(um >> 16), a1);
        }
        unsigned int packed = (unsigned int)f2bf(fmaxf(a0, 0.f)) |
                              ((unsigned int)f2bf(fmaxf(a1, 0.f)) << 16);
        *(unsigned int*)(SH1 + (size_t)s * 192 + j) = packed;
    }
}

extern "C" void kernel_launch(void* const* d_in, const int* in_sizes, int n_in,
                              void* d_out, int out_size, void* d_ws, size_t ws_size,
                              hipStream_t stream) {
    const float* states = (const float*)d_in[0];
    const float* embeds = (const float*)d_in[1];
    const int* span_starts = (const int*)d_in[2];
    const int* span_lengths = (const int*)d_in[3];
    const float* Wa1 = (const float*)d_in[4];
    const float* ba1 = (const float*)d_in[5];
    const float* Wa2 = (const float*)d_in[6];
    const float* ba2 = (const float*)d_in[7];
    const float* Wa3 = (const float*)d_in[8];
    const float* ba3 = (const float*)d_in[9];
    const float* width_table = (const float*)d_in[10];
    const float* Ws1 = (const float*)d_in[11];
    const float* bs1 = (const float*)d_in[12];
    const float* Ws2 = (const float*)d_in[13];
    const float* bs2 = (const float*)d_in[14];
    const float* Ws3 = (const float*)d_in[15];
    const float* bs3 = (const float*)d_in[16];
    float* out = (float*)d_out;

    // ---- workspace layout ----
    char* w = (char*)d_ws;
    unsigned short* WtA  = (unsigned short*)w;  w += 480 * 1024 * 2;
    unsigned short* WtE  = (unsigned short*)w;  w += 160 * 512 * 2;
    unsigned short* Wa2t = (unsigned short*)w;  w += 160 * 192 * 2;
    unsigned short* Ws2t = (unsigned short*)w;  w += 160 * 192 * 2;
    float* PW    = (float*)w;                   w += 5632;
    float* attns = (float*)w;                   w += 8192 * 4;
    unsigned short* Psh = (unsigned short*)w;   w += (size_t)T_TOK * 160 * 2;   // bf16
    unsigned short* Peh = (unsigned short*)w;   w += (size_t)T_TOK * 160 * 2;   // bf16
    unsigned short* Pmh = (unsigned short*)w;   w += (size_t)T_TOK * 160 * 2;   // bf16
    unsigned short* H1A = (unsigned short*)w;   w += (size_t)T_TOK * 192 * 2;   // bf16
    unsigned short* SH1 = (unsigned short*)w;   w += (size_t)S_SPAN * 192 * 2;  // bf16
    // No memsets: pad cols (0xAA poison = finite bf16) multiply zeroed W rows.

    // ---- prep: weight transposes + width proj (71 blocks) ----
    PrepTab pt;
    pt.g[0] = { Wa1,              WtA,              1024, 1024, (160*1024 + 255)/256 };
    pt.g[1] = { Ws1,              WtA + 160*1024,   1024, 1024, (160*1024 + 255)/256 };
    pt.g[2] = { Ws1 + 1024*150,   WtA + 320*1024,   1024, 1024, (160*1024 + 255)/256 };
    pt.g[3] = { Ws1 + 2048*150,   WtE,               512,  512, (160*512  + 255)/256 };
    pt.g[4] = { Wa2,              Wa2t,              150,  192, (160*192  + 255)/256 };
    pt.g[5] = { Ws2,              Ws2t,              150,  192, (160*192  + 255)/256 };
    pt.wt = width_table; pt.Ws1w = Ws1 + 2560*150; pt.PW = PW;
    int wblk = 0; for (int i = 0; i < 6; ++i) wblk += pt.g[i].nblk;
    prep_kernel<<<wblk + 9, 256, 0, stream>>>(pt);

    GG z = {};

    // ---- fused GEMM1+2: 4 groups, fp32 A read directly, 512 blocks ----
    GTab t1; t1.ng = 4;
    t1.g[0] = z; t1.g[0].A = states; t1.g[0].lda = 1024; t1.g[0].W = WtA;            t1.g[0].K = 1024;
    t1.g[0].nrb = 128; t1.g[0].outh = H1A; t1.g[0].ldo = 192; t1.g[0].bias = ba1; t1.g[0].relu = 1;
    t1.g[1] = z; t1.g[1].A = states; t1.g[1].lda = 1024; t1.g[1].W = WtA + 160*1024; t1.g[1].K = 1024;
    t1.g[1].nrb = 128; t1.g[1].outh = Psh; t1.g[1].ldo = 160;
    t1.g[2] = z; t1.g[2].A = states; t1.g[2].lda = 1024; t1.g[2].W = WtA + 320*1024; t1.g[2].K = 1024;
    t1.g[2].nrb = 128; t1.g[2].outh = Peh; t1.g[2].ldo = 160;
    t1.g[3] = z; t1.g[3].A = embeds; t1.g[3].lda = 512;  t1.g[3].W = WtE;            t1.g[3].K = 512;
    t1.g[3].nrb = 128; t1.g[3].outh = Pmh; t1.g[3].ldo = 160;
    gemm_fused<1, true><<<512, 256, 0, stream>>>(t1);

    // ---- attn layer2 + fused layer3 dot -> attns ----
    GTab t2; t2.ng = 1;
    t2.g[0] = z; t2.g[0].A = H1A; t2.g[0].lda = 192; t2.g[0].W = Wa2t; t2.g[0].K = 192;
    t2.g[0].nrb = 128; t2.g[0].bias = ba2; t2.g[0].dotv = Wa3; t2.g[0].dotb = ba3; t2.g[0].dotout = attns;
    gemm_fused<2, false><<<128, 256, 0, stream>>>(t2);

    // ---- span layer1 -> SH1 (bf16) ----
    span_l1_kernel<<<S_SPAN / 4, 256, 0, stream>>>(attns, span_starts, span_lengths,
                                                   Psh, Peh, Pmh, PW, bs1, SH1);

    // ---- span layer2 + fused layer3 dot -> out ----
    GTab t3; t3.ng = 1;
    t3.g[0] = z; t3.g[0].A = SH1; t3.g[0].lda = 192; t3.g[0].W = Ws2t; t3.g[0].K = 192;
    t3.g[0].nrb = 512; t3.g[0].bias = bs2; t3.g[0].dotv = Ws3; t3.g[0].dotb = bs3; t3.g[0].dotout = out;
    gemm_fused<3, false><<<512, 256, 0, stream>>>(t3);
}

// Round 14
// 167.727 us; speedup vs baseline: 1.1356x; 1.0316x over previous
//
#include <hip/hip_runtime.h>
#include <math.h>

#define T_TOK 8192
#define A_DIM 1024
#define E_DIM 512
#define S_SPAN 32768
#define HID 150

typedef __attribute__((ext_vector_type(8))) short short8;
typedef __attribute__((ext_vector_type(4))) float f32x4;
typedef __attribute__((ext_vector_type(4))) unsigned int u32x4;

__device__ __forceinline__ unsigned short f2bf(float f) {
    unsigned int u = __builtin_bit_cast(unsigned int, f);
    u += 0x7FFFu + ((u >> 16) & 1u);          // RNE
    return (unsigned short)(u >> 16);
}
__device__ __forceinline__ float bf2f(unsigned int h16) {
    unsigned int u = h16 << 16;
    return __builtin_bit_cast(float, u);
}
__device__ __forceinline__ short8 cast8(f32x4 a, f32x4 b) {
    short8 r;
    r[0] = (short)f2bf(a.x); r[1] = (short)f2bf(a.y);
    r[2] = (short)f2bf(a.z); r[3] = (short)f2bf(a.w);
    r[4] = (short)f2bf(b.x); r[5] = (short)f2bf(b.y);
    r[6] = (short)f2bf(b.z); r[7] = (short)f2bf(b.w);
    return r;
}

// ---------------------------------------------------------------------------
// prep: 6 weight transposes + width projection (71 blocks; no input cast)
// ---------------------------------------------------------------------------
struct WConv { const float* src; unsigned short* dst; int K0; int Kpad; int nblk; };
struct PrepTab {
    WConv g[6];
    const float* wt; const float* Ws1w; float* PW;
};

__global__ __launch_bounds__(256) void prep_kernel(PrepTab tab) {
    int b = blockIdx.x;
    #pragma unroll
    for (int gi = 0; gi < 6; ++gi) {
        if (b < tab.g[gi].nblk) {
            int idx = b * 256 + threadIdx.x;               // idx = k*160 + j
            int Kpad = tab.g[gi].Kpad;
            if (idx < Kpad * 160) {
                int k = idx / 160, j = idx - k * 160;
                float v = (j < HID && k < tab.g[gi].K0)
                          ? tab.g[gi].src[(size_t)k * HID + j] : 0.f;   // coalesced read
                tab.g[gi].dst[(size_t)j * Kpad + k] = f2bf(v);          // scattered write
            }
            return;
        }
        b -= tab.g[gi].nblk;
    }
    // width projection: 9 blocks
    int j = threadIdx.x;
    if (j < HID) {
        float acc = 0.f;
        for (int k = 0; k < 20; ++k)
            acc = fmaf(tab.wt[b * 20 + k], tab.Ws1w[k * HID + j], acc);
        tab.PW[b * HID + j] = acc;
    }
}

// ---------------------------------------------------------------------------
// unified MFMA GEMM (R13 structure): dbuf BK=64, LDW=72 (46 KB, 3 blocks/CU).
// AF32: A fp32, cast to bf16 in-register AFTER the MFMA block (RNE, bit-
// identical to a pre-cast pass).
// ---------------------------------------------------------------------------
struct GG {
    const void* A; int lda;
    const unsigned short* W; int K; int nrb;
    unsigned short* outh; int ldo;
    const float* bias; int relu;
    const float* dotv; const float* dotb; float* dotout;
};
struct GTab { GG g[4]; int ng; };

template <int TAG, bool AF32>
__global__ __launch_bounds__(256) void gemm_fused(GTab tab) {
    constexpr int LDW = 72;
    __shared__ unsigned short WtL[2][160 * LDW];

    int b = blockIdx.x;
    int gi = 0;
    while (gi < tab.ng - 1 && b >= tab.g[gi].nrb) { b -= tab.g[gi].nrb; ++gi; }
    const GG G = tab.g[gi];

    const int tid = threadIdx.x;
    const int wid = tid >> 6;
    const int lane = tid & 63;
    const int l15 = lane & 15;
    const int quad = lane >> 4;
    const int row0 = b * 64 + wid * 16 + l15;
    const int K = G.K;
    const int nch = K >> 6;
    const float* Af = (const float*)G.A + (size_t)row0 * G.lda;
    const unsigned short* Ah = (const unsigned short*)G.A + (size_t)row0 * G.lda;

    u32x4 stg[5];
    int sn[5], sk[5];
    #pragma unroll
    for (int i = 0; i < 5; ++i) { int u = tid + i * 256; sn[i] = u >> 3; sk[i] = (u & 7) * 8; }

    f32x4 acc[10];
    #pragma unroll
    for (int nt = 0; nt < 10; ++nt) acc[nt] = (f32x4){0.f, 0.f, 0.f, 0.f};

    #pragma unroll
    for (int i = 0; i < 5; ++i)
        stg[i] = *(const u32x4*)(G.W + (size_t)sn[i] * K + sk[i]);
    short8 avc0, avc1;
    if (AF32) {
        f32x4 f0 = *(const f32x4*)(Af + quad * 8);
        f32x4 f1 = *(const f32x4*)(Af + quad * 8 + 4);
        f32x4 f2 = *(const f32x4*)(Af + 32 + quad * 8);
        f32x4 f3 = *(const f32x4*)(Af + 32 + quad * 8 + 4);
        avc0 = cast8(f0, f1);
        avc1 = cast8(f2, f3);
    } else {
        avc0 = *(const short8*)(Ah + quad * 8);
        avc1 = *(const short8*)(Ah + 32 + quad * 8);
    }
    #pragma unroll
    for (int i = 0; i < 5; ++i)
        *(u32x4*)&WtL[0][sn[i] * LDW + sk[i]] = stg[i];
    __syncthreads();

    for (int c = 0; c < nch; ++c) {
        const int pb = c & 1;
        short8 avn0, avn1;
        f32x4 fn0, fn1, fn2, fn3;
        const bool more = (c + 1 < nch);
        if (more) {
            const int kn = (c + 1) << 6;
            #pragma unroll
            for (int i = 0; i < 5; ++i)
                stg[i] = *(const u32x4*)(G.W + (size_t)sn[i] * K + kn + sk[i]);
            if (AF32) {
                fn0 = *(const f32x4*)(Af + kn + quad * 8);
                fn1 = *(const f32x4*)(Af + kn + quad * 8 + 4);
                fn2 = *(const f32x4*)(Af + kn + 32 + quad * 8);
                fn3 = *(const f32x4*)(Af + kn + 32 + quad * 8 + 4);
            } else {
                avn0 = *(const short8*)(Ah + kn + quad * 8);
                avn1 = *(const short8*)(Ah + kn + 32 + quad * 8);
            }
        }
        #pragma unroll
        for (int nt = 0; nt < 10; ++nt) {
            short8 bv0 = *(const short8*)&WtL[pb][(nt * 16 + l15) * LDW + quad * 8];
            acc[nt] = __builtin_amdgcn_mfma_f32_16x16x32_bf16(avc0, bv0, acc[nt], 0, 0, 0);
            short8 bv1 = *(const short8*)&WtL[pb][(nt * 16 + l15) * LDW + 32 + quad * 8];
            acc[nt] = __builtin_amdgcn_mfma_f32_16x16x32_bf16(avc1, bv1, acc[nt], 0, 0, 0);
        }
        if (more) {
            #pragma unroll
            for (int i = 0; i < 5; ++i)
                *(u32x4*)&WtL[pb ^ 1][sn[i] * LDW + sk[i]] = stg[i];
            if (AF32) {
                avc0 = cast8(fn0, fn1);
                avc1 = cast8(fn2, fn3);
            } else {
                avc0 = avn0; avc1 = avn1;
            }
        }
        __syncthreads();
    }

    const int rbase = b * 64 + wid * 16 + quad * 4;
    if (G.dotout) {
        float part[4] = {0.f, 0.f, 0.f, 0.f};
        #pragma unroll
        for (int nt = 0; nt < 10; ++nt) {
            int col = nt * 16 + l15;
            float bv_ = (col < HID) ? G.bias[col] : 0.f;
            float vv = (col < HID) ? G.dotv[col] : 0.f;
            #pragma unroll
            for (int r = 0; r < 4; ++r)
                part[r] += fmaxf(acc[nt][r] + bv_, 0.f) * vv;
        }
        #pragma unroll
        for (int r = 0; r < 4; ++r) {
            float p = part[r];
            #pragma unroll
            for (int off = 1; off < 16; off <<= 1) p += __shfl_xor(p, off);
            if (l15 == 0) G.dotout[rbase + r] = p + G.dotb[0];
        }
    } else {
        #pragma unroll
        for (int nt = 0; nt < 10; ++nt) {
            int col = nt * 16 + l15;
            float bv_ = (G.bias != nullptr && col < HID) ? G.bias[col] : 0.f;
            #pragma unroll
            for (int r = 0; r < 4; ++r) {
                int row = rbase + r;
                float v = acc[nt][r] + bv_;
                if (G.relu) v = fmaxf(v, 0.f);
                G.outh[(size_t)row * G.ldo + col] = f2bf(v);
            }
        }
    }
}

// ---------------------------------------------------------------------------
// span layer-1: one span per 16-LANE GROUP (4 spans/wave, 16/block).
// softmax reduce confined to the group (len<=9 < 16; xor offs 8..1);
// p-loop: 5 iterations at 94% utilization (was 2 at 59% with wave/span).
// ---------------------------------------------------------------------------
__global__ __launch_bounds__(256) void span_l1_kernel(const float* __restrict__ attns,
                                                      const int* __restrict__ starts,
                                                      const int* __restrict__ lens,
                                                      const unsigned short* __restrict__ Ps,
                                                      const unsigned short* __restrict__ Pe,
                                                      const unsigned short* __restrict__ Pm,
                                                      const float* __restrict__ PW,
                                                      const float* __restrict__ bs1,
                                                      unsigned short* __restrict__ SH1) {
    const int wid = threadIdx.x >> 6;
    const int lane = threadIdx.x & 63;
    const int grp = lane >> 4;        // 4 spans per wave
    const int hl = lane & 15;
    const int gbase = lane & 48;      // first lane of this group (within wave)
    const int s = blockIdx.x * 16 + wid * 4 + grp;
    const int start = starts[s];
    const int len = lens[s];

    const int iv = min(start + hl, T_TOK - 1);
    float a = (hl <= len) ? attns[iv] : -INFINITY;
    float m = a;
    #pragma unroll
    for (int off = 8; off; off >>= 1) m = fmaxf(m, __shfl_xor(m, off));
    float e = (hl <= len) ? __expf(a - m) : 0.f;
    float ssum = e;
    #pragma unroll
    for (int off = 8; off; off >>= 1) ssum += __shfl_xor(ssum, off);
    float wv = e / ssum;

    float wl[10]; int il[10];
    #pragma unroll
    for (int l = 0; l < 10; ++l) {
        wl[l] = __shfl(wv, gbase + l);
        il[l] = __shfl(iv, gbase + l);
    }

    const int end = start + len;
    const int width = len + 1;
    const int bucket = (width >= 1) + (width >= 2) + (width >= 3) + (width >= 4) +
                       (width >= 8) + (width >= 16) + (width >= 32) + (width >= 64);

    const unsigned short* ps = Ps + (size_t)start * 160;
    const unsigned short* pe = Pe + (size_t)end * 160;
    const float* pw = PW + bucket * HID;

    for (int p = hl; p < 75; p += 16) {
        const int j = 2 * p;
        unsigned int u0 = *(const unsigned int*)(ps + j);
        unsigned int u1 = *(const unsigned int*)(pe + j);
        float a0 = bs1[j]     + bf2f(u0 & 0xffff) + bf2f(u1 & 0xffff) + pw[j];
        float a1 = bs1[j + 1] + bf2f(u0 >> 16)    + bf2f(u1 >> 16)    + pw[j + 1];
        #pragma unroll
        for (int l = 0; l < 10; ++l) {
            unsigned int um = *(const unsigned int*)(Pm + (size_t)il[l] * 160 + j);
            a0 = fmaf(wl[l], bf2f(um & 0xffff), a0);
            a1 = fmaf(wl[l], bf2f(um >> 16), a1);
        }
        unsigned int packed = (unsigned int)f2bf(fmaxf(a0, 0.f)) |
                              ((unsigned int)f2bf(fmaxf(a1, 0.f)) << 16);
        *(unsigned int*)(SH1 + (size_t)s * 192 + j) = packed;
    }
}

extern "C" void kernel_launch(void* const* d_in, const int* in_sizes, int n_in,
                              void* d_out, int out_size, void* d_ws, size_t ws_size,
                              hipStream_t stream) {
    const float* states = (const float*)d_in[0];
    const float* embeds = (const float*)d_in[1];
    const int* span_starts = (const int*)d_in[2];
    const int* span_lengths = (const int*)d_in[3];
    const float* Wa1 = (const float*)d_in[4];
    const float* ba1 = (const float*)d_in[5];
    const float* Wa2 = (const float*)d_in[6];
    const float* ba2 = (const float*)d_in[7];
    const float* Wa3 = (const float*)d_in[8];
    const float* ba3 = (const float*)d_in[9];
    const float* width_table = (const float*)d_in[10];
    const float* Ws1 = (const float*)d_in[11];
    const float* bs1 = (const float*)d_in[12];
    const float* Ws2 = (const float*)d_in[13];
    const float* bs2 = (const float*)d_in[14];
    const float* Ws3 = (const float*)d_in[15];
    const float* bs3 = (const float*)d_in[16];
    float* out = (float*)d_out;

    // ---- workspace layout ----
    char* w = (char*)d_ws;
    unsigned short* WtA  = (unsigned short*)w;  w += 480 * 1024 * 2;
    unsigned short* WtE  = (unsigned short*)w;  w += 160 * 512 * 2;
    unsigned short* Wa2t = (unsigned short*)w;  w += 160 * 192 * 2;
    unsigned short* Ws2t = (unsigned short*)w;  w += 160 * 192 * 2;
    float* PW    = (float*)w;                   w += 5632;
    float* attns = (float*)w;                   w += 8192 * 4;
    unsigned short* Psh = (unsigned short*)w;   w += (size_t)T_TOK * 160 * 2;   // bf16
    unsigned short* Peh = (unsigned short*)w;   w += (size_t)T_TOK * 160 * 2;   // bf16
    unsigned short* Pmh = (unsigned short*)w;   w += (size_t)T_TOK * 160 * 2;   // bf16
    unsigned short* H1A = (unsigned short*)w;   w += (size_t)T_TOK * 192 * 2;   // bf16
    unsigned short* SH1 = (unsigned short*)w;   w += (size_t)S_SPAN * 192 * 2;  // bf16
    // No memsets: pad cols (0xAA poison = finite bf16) multiply zeroed W rows.

    // ---- prep: weight transposes + width proj (71 blocks) ----
    PrepTab pt;
    pt.g[0] = { Wa1,              WtA,              1024, 1024, (160*1024 + 255)/256 };
    pt.g[1] = { Ws1,              WtA + 160*1024,   1024, 1024, (160*1024 + 255)/256 };
    pt.g[2] = { Ws1 + 1024*150,   WtA + 320*1024,   1024, 1024, (160*1024 + 255)/256 };
    pt.g[3] = { Ws1 + 2048*150,   WtE,               512,  512, (160*512  + 255)/256 };
    pt.g[4] = { Wa2,              Wa2t,              150,  192, (160*192  + 255)/256 };
    pt.g[5] = { Ws2,              Ws2t,              150,  192, (160*192  + 255)/256 };
    pt.wt = width_table; pt.Ws1w = Ws1 + 2560*150; pt.PW = PW;
    int wblk = 0; for (int i = 0; i < 6; ++i) wblk += pt.g[i].nblk;
    prep_kernel<<<wblk + 9, 256, 0, stream>>>(pt);

    GG z = {};

    // ---- fused GEMM1+2: 4 groups, fp32 A read directly, 512 blocks ----
    GTab t1; t1.ng = 4;
    t1.g[0] = z; t1.g[0].A = states; t1.g[0].lda = 1024; t1.g[0].W = WtA;            t1.g[0].K = 1024;
    t1.g[0].nrb = 128; t1.g[0].outh = H1A; t1.g[0].ldo = 192; t1.g[0].bias = ba1; t1.g[0].relu = 1;
    t1.g[1] = z; t1.g[1].A = states; t1.g[1].lda = 1024; t1.g[1].W = WtA + 160*1024; t1.g[1].K = 1024;
    t1.g[1].nrb = 128; t1.g[1].outh = Psh; t1.g[1].ldo = 160;
    t1.g[2] = z; t1.g[2].A = states; t1.g[2].lda = 1024; t1.g[2].W = WtA + 320*1024; t1.g[2].K = 1024;
    t1.g[2].nrb = 128; t1.g[2].outh = Peh; t1.g[2].ldo = 160;
    t1.g[3] = z; t1.g[3].A = embeds; t1.g[3].lda = 512;  t1.g[3].W = WtE;            t1.g[3].K = 512;
    t1.g[3].nrb = 128; t1.g[3].outh = Pmh; t1.g[3].ldo = 160;
    gemm_fused<1, true><<<512, 256, 0, stream>>>(t1);

    // ---- attn layer2 + fused layer3 dot -> attns ----
    GTab t2; t2.ng = 1;
    t2.g[0] = z; t2.g[0].A = H1A; t2.g[0].lda = 192; t2.g[0].W = Wa2t; t2.g[0].K = 192;
    t2.g[0].nrb = 128; t2.g[0].bias = ba2; t2.g[0].dotv = Wa3; t2.g[0].dotb = ba3; t2.g[0].dotout = attns;
    gemm_fused<2, false><<<128, 256, 0, stream>>>(t2);

    // ---- span layer1 -> SH1 (bf16), 16 spans/block ----
    span_l1_kernel<<<S_SPAN / 16, 256, 0, stream>>>(attns, span_starts, span_lengths,
                                                    Psh, Peh, Pmh, PW, bs1, SH1);

    // ---- span layer2 + fused layer3 dot -> out ----
    GTab t3; t3.ng = 1;
    t3.g[0] = z; t3.g[0].A = SH1; t3.g[0].lda = 192; t3.g[0].W = Ws2t; t3.g[0].K = 192;
    t3.g[0].nrb = 512; t3.g[0].bias = bs2; t3.g[0].dotv = Ws3; t3.g[0].dotb = bs3; t3.g[0].dotout = out;
    gemm_fused<3, false><<<512, 256, 0, stream>>>(t3);
}

// Round 15
// 164.769 us; speedup vs baseline: 1.1559x; 1.0180x over previous
//
#include <hip/hip_runtime.h>
#include <math.h>

#define T_TOK 8192
#define A_DIM 1024
#define E_DIM 512
#define S_SPAN 32768
#define HID 150

typedef __attribute__((ext_vector_type(8))) short short8;
typedef __attribute__((ext_vector_type(4))) float f32x4;
typedef __attribute__((ext_vector_type(4))) unsigned int u32x4;

__device__ __forceinline__ unsigned short f2bf(float f) {
    unsigned int u = __builtin_bit_cast(unsigned int, f);
    u += 0x7FFFu + ((u >> 16) & 1u);          // RNE
    return (unsigned short)(u >> 16);
}
__device__ __forceinline__ float bf2f(unsigned int h16) {
    unsigned int u = h16 << 16;
    return __builtin_bit_cast(float, u);
}
__device__ __forceinline__ short8 cast8(f32x4 a, f32x4 b) {
    short8 r;
    r[0] = (short)f2bf(a.x); r[1] = (short)f2bf(a.y);
    r[2] = (short)f2bf(a.z); r[3] = (short)f2bf(a.w);
    r[4] = (short)f2bf(b.x); r[5] = (short)f2bf(b.y);
    r[6] = (short)f2bf(b.z); r[7] = (short)f2bf(b.w);
    return r;
}

// ---------------------------------------------------------------------------
// prep: 6 weight transposes + width projection (71 blocks; no input cast)
// ---------------------------------------------------------------------------
struct WConv { const float* src; unsigned short* dst; int K0; int Kpad; int nblk; };
struct PrepTab {
    WConv g[6];
    const float* wt; const float* Ws1w; float* PW;
};

__global__ __launch_bounds__(256) void prep_kernel(PrepTab tab) {
    int b = blockIdx.x;
    #pragma unroll
    for (int gi = 0; gi < 6; ++gi) {
        if (b < tab.g[gi].nblk) {
            int idx = b * 256 + threadIdx.x;               // idx = k*160 + j
            int Kpad = tab.g[gi].Kpad;
            if (idx < Kpad * 160) {
                int k = idx / 160, j = idx - k * 160;
                float v = (j < HID && k < tab.g[gi].K0)
                          ? tab.g[gi].src[(size_t)k * HID + j] : 0.f;   // coalesced read
                tab.g[gi].dst[(size_t)j * Kpad + k] = f2bf(v);          // scattered write
            }
            return;
        }
        b -= tab.g[gi].nblk;
    }
    // width projection: 9 blocks
    int j = threadIdx.x;
    if (j < HID) {
        float acc = 0.f;
        for (int k = 0; k < 20; ++k)
            acc = fmaf(tab.wt[b * 20 + k], tab.Ws1w[k * HID + j], acc);
        tab.PW[b * HID + j] = acc;
    }
}

// ---------------------------------------------------------------------------
// unified MFMA GEMM (R13 structure): dbuf BK=64, LDW=72 (46 KB, 3 blocks/CU).
// AF32: A fp32, cast to bf16 in-register AFTER the MFMA block.
// NEW: W2 path — fused attn layer2+3 in group-0 epilogue. h1 (16x160/wave)
// goes to a per-wave LDS tile (aliases WtL, dead after final barrier; no
// cross-wave sharing -> no barrier), re-read in MFMA A-layout, 5x10 MFMAs
// vs Wa2t, then dot epilogue -> attns. Bit-identical to the old t2 dispatch
// (same bf16 rounding; old K=192 pad chunks added exact zeros).
// ---------------------------------------------------------------------------
struct GG {
    const void* A; int lda;
    const unsigned short* W; int K; int nrb;
    unsigned short* outh; int ldo;
    const float* bias; int relu;
    const float* dotv; const float* dotb; float* dotout;
    const unsigned short* W2; const float* bias2;
};
struct GTab { GG g[4]; int ng; };

template <int TAG, bool AF32>
__global__ __launch_bounds__(256) void gemm_fused(GTab tab) {
    constexpr int LDW = 72;
    __shared__ unsigned short WtL[2][160 * LDW];

    int b = blockIdx.x;
    int gi = 0;
    while (gi < tab.ng - 1 && b >= tab.g[gi].nrb) { b -= tab.g[gi].nrb; ++gi; }
    const GG G = tab.g[gi];

    const int tid = threadIdx.x;
    const int wid = tid >> 6;
    const int lane = tid & 63;
    const int l15 = lane & 15;
    const int quad = lane >> 4;
    const int row0 = b * 64 + wid * 16 + l15;
    const int K = G.K;
    const int nch = K >> 6;
    const float* Af = (const float*)G.A + (size_t)row0 * G.lda;
    const unsigned short* Ah = (const unsigned short*)G.A + (size_t)row0 * G.lda;

    u32x4 stg[5];
    int sn[5], sk[5];
    #pragma unroll
    for (int i = 0; i < 5; ++i) { int u = tid + i * 256; sn[i] = u >> 3; sk[i] = (u & 7) * 8; }

    f32x4 acc[10];
    #pragma unroll
    for (int nt = 0; nt < 10; ++nt) acc[nt] = (f32x4){0.f, 0.f, 0.f, 0.f};

    #pragma unroll
    for (int i = 0; i < 5; ++i)
        stg[i] = *(const u32x4*)(G.W + (size_t)sn[i] * K + sk[i]);
    short8 avc0, avc1;
    if (AF32) {
        f32x4 f0 = *(const f32x4*)(Af + quad * 8);
        f32x4 f1 = *(const f32x4*)(Af + quad * 8 + 4);
        f32x4 f2 = *(const f32x4*)(Af + 32 + quad * 8);
        f32x4 f3 = *(const f32x4*)(Af + 32 + quad * 8 + 4);
        avc0 = cast8(f0, f1);
        avc1 = cast8(f2, f3);
    } else {
        avc0 = *(const short8*)(Ah + quad * 8);
        avc1 = *(const short8*)(Ah + 32 + quad * 8);
    }
    #pragma unroll
    for (int i = 0; i < 5; ++i)
        *(u32x4*)&WtL[0][sn[i] * LDW + sk[i]] = stg[i];
    __syncthreads();

    for (int c = 0; c < nch; ++c) {
        const int pb = c & 1;
        short8 avn0, avn1;
        f32x4 fn0, fn1, fn2, fn3;
        const bool more = (c + 1 < nch);
        if (more) {
            const int kn = (c + 1) << 6;
            #pragma unroll
            for (int i = 0; i < 5; ++i)
                stg[i] = *(const u32x4*)(G.W + (size_t)sn[i] * K + kn + sk[i]);
            if (AF32) {
                fn0 = *(const f32x4*)(Af + kn + quad * 8);
                fn1 = *(const f32x4*)(Af + kn + quad * 8 + 4);
                fn2 = *(const f32x4*)(Af + kn + 32 + quad * 8);
                fn3 = *(const f32x4*)(Af + kn + 32 + quad * 8 + 4);
            } else {
                avn0 = *(const short8*)(Ah + kn + quad * 8);
                avn1 = *(const short8*)(Ah + kn + 32 + quad * 8);
            }
        }
        #pragma unroll
        for (int nt = 0; nt < 10; ++nt) {
            short8 bv0 = *(const short8*)&WtL[pb][(nt * 16 + l15) * LDW + quad * 8];
            acc[nt] = __builtin_amdgcn_mfma_f32_16x16x32_bf16(avc0, bv0, acc[nt], 0, 0, 0);
            short8 bv1 = *(const short8*)&WtL[pb][(nt * 16 + l15) * LDW + 32 + quad * 8];
            acc[nt] = __builtin_amdgcn_mfma_f32_16x16x32_bf16(avc1, bv1, acc[nt], 0, 0, 0);
        }
        if (more) {
            #pragma unroll
            for (int i = 0; i < 5; ++i)
                *(u32x4*)&WtL[pb ^ 1][sn[i] * LDW + sk[i]] = stg[i];
            if (AF32) {
                avc0 = cast8(fn0, fn1);
                avc1 = cast8(fn2, fn3);
            } else {
                avc0 = avn0; avc1 = avn1;
            }
        }
        __syncthreads();
    }

    const int rbase = b * 64 + wid * 16 + quad * 4;
    if (G.W2) {
        // ---- fused attn layer2+3 ----
        constexpr int LDH = 168;   // 336 B row stride, 16B-aligned
        unsigned short* tile = &WtL[0][0] + wid * 16 * LDH;   // per-wave region
        #pragma unroll
        for (int nt = 0; nt < 10; ++nt) {
            int col = nt * 16 + l15;
            float bv_ = (col < HID) ? G.bias[col] : 0.f;
            #pragma unroll
            for (int r = 0; r < 4; ++r) {
                float v = fmaxf(acc[nt][r] + bv_, 0.f);
                tile[(quad * 4 + r) * LDH + col] = f2bf(v);   // h1, C-layout write
            }
        }
        // same-wave RAW through LDS: compiler inserts lgkmcnt; no barrier.
        f32x4 acc2[10];
        #pragma unroll
        for (int nt = 0; nt < 10; ++nt) acc2[nt] = (f32x4){0.f, 0.f, 0.f, 0.f};
        #pragma unroll
        for (int kc = 0; kc < 5; ++kc) {
            short8 av = *(const short8*)&tile[l15 * LDH + kc * 32 + quad * 8];
            #pragma unroll
            for (int nt = 0; nt < 10; ++nt) {
                short8 bv = *(const short8*)(G.W2 + (size_t)(nt * 16 + l15) * 192 + kc * 32 + quad * 8);
                acc2[nt] = __builtin_amdgcn_mfma_f32_16x16x32_bf16(av, bv, acc2[nt], 0, 0, 0);
            }
        }
        float part[4] = {0.f, 0.f, 0.f, 0.f};
        #pragma unroll
        for (int nt = 0; nt < 10; ++nt) {
            int col = nt * 16 + l15;
            float b2 = (col < HID) ? G.bias2[col] : 0.f;
            float vv = (col < HID) ? G.dotv[col] : 0.f;
            #pragma unroll
            for (int r = 0; r < 4; ++r)
                part[r] += fmaxf(acc2[nt][r] + b2, 0.f) * vv;
        }
        #pragma unroll
        for (int r = 0; r < 4; ++r) {
            float p = part[r];
            #pragma unroll
            for (int off = 1; off < 16; off <<= 1) p += __shfl_xor(p, off);
            if (l15 == 0) G.dotout[rbase + r] = p + G.dotb[0];
        }
    } else if (G.dotout) {
        float part[4] = {0.f, 0.f, 0.f, 0.f};
        #pragma unroll
        for (int nt = 0; nt < 10; ++nt) {
            int col = nt * 16 + l15;
            float bv_ = (col < HID) ? G.bias[col] : 0.f;
            float vv = (col < HID) ? G.dotv[col] : 0.f;
            #pragma unroll
            for (int r = 0; r < 4; ++r)
                part[r] += fmaxf(acc[nt][r] + bv_, 0.f) * vv;
        }
        #pragma unroll
        for (int r = 0; r < 4; ++r) {
            float p = part[r];
            #pragma unroll
            for (int off = 1; off < 16; off <<= 1) p += __shfl_xor(p, off);
            if (l15 == 0) G.dotout[rbase + r] = p + G.dotb[0];
        }
    } else {
        #pragma unroll
        for (int nt = 0; nt < 10; ++nt) {
            int col = nt * 16 + l15;
            float bv_ = (G.bias != nullptr && col < HID) ? G.bias[col] : 0.f;
            #pragma unroll
            for (int r = 0; r < 4; ++r) {
                int row = rbase + r;
                float v = acc[nt][r] + bv_;
                if (G.relu) v = fmaxf(v, 0.f);
                G.outh[(size_t)row * G.ldo + col] = f2bf(v);
            }
        }
    }
}

// ---------------------------------------------------------------------------
// span layer-1: one span per 16-lane group (4/wave, 16/block).
// ---------------------------------------------------------------------------
__global__ __launch_bounds__(256) void span_l1_kernel(const float* __restrict__ attns,
                                                      const int* __restrict__ starts,
                                                      const int* __restrict__ lens,
                                                      const unsigned short* __restrict__ Ps,
                                                      const unsigned short* __restrict__ Pe,
                                                      const unsigned short* __restrict__ Pm,
                                                      const float* __restrict__ PW,
                                                      const float* __restrict__ bs1,
                                                      unsigned short* __restrict__ SH1) {
    const int wid = threadIdx.x >> 6;
    const int lane = threadIdx.x & 63;
    const int grp = lane >> 4;
    const int hl = lane & 15;
    const int gbase = lane & 48;
    const int s = blockIdx.x * 16 + wid * 4 + grp;
    const int start = starts[s];
    const int len = lens[s];

    const int iv = min(start + hl, T_TOK - 1);
    float a = (hl <= len) ? attns[iv] : -INFINITY;
    float m = a;
    #pragma unroll
    for (int off = 8; off; off >>= 1) m = fmaxf(m, __shfl_xor(m, off));
    float e = (hl <= len) ? __expf(a - m) : 0.f;
    float ssum = e;
    #pragma unroll
    for (int off = 8; off; off >>= 1) ssum += __shfl_xor(ssum, off);
    float wv = e / ssum;

    float wl[10]; int il[10];
    #pragma unroll
    for (int l = 0; l < 10; ++l) {
        wl[l] = __shfl(wv, gbase + l);
        il[l] = __shfl(iv, gbase + l);
    }

    const int end = start + len;
    const int width = len + 1;
    const int bucket = (width >= 1) + (width >= 2) + (width >= 3) + (width >= 4) +
                       (width >= 8) + (width >= 16) + (width >= 32) + (width >= 64);

    const unsigned short* ps = Ps + (size_t)start * 160;
    const unsigned short* pe = Pe + (size_t)end * 160;
    const float* pw = PW + bucket * HID;

    for (int p = hl; p < 75; p += 16) {
        const int j = 2 * p;
        unsigned int u0 = *(const unsigned int*)(ps + j);
        unsigned int u1 = *(const unsigned int*)(pe + j);
        float a0 = bs1[j]     + bf2f(u0 & 0xffff) + bf2f(u1 & 0xffff) + pw[j];
        float a1 = bs1[j + 1] + bf2f(u0 >> 16)    + bf2f(u1 >> 16)    + pw[j + 1];
        #pragma unroll
        for (int l = 0; l < 10; ++l) {
            unsigned int um = *(const unsigned int*)(Pm + (size_t)il[l] * 160 + j);
            a0 = fmaf(wl[l], bf2f(um & 0xffff), a0);
            a1 = fmaf(wl[l], bf2f(um >> 16), a1);
        }
        unsigned int packed = (unsigned int)f2bf(fmaxf(a0, 0.f)) |
                              ((unsigned int)f2bf(fmaxf(a1, 0.f)) << 16);
        *(unsigned int*)(SH1 + (size_t)s * 192 + j) = packed;
    }
}

extern "C" void kernel_launch(void* const* d_in, const int* in_sizes, int n_in,
                              void* d_out, int out_size, void* d_ws, size_t ws_size,
                              hipStream_t stream) {
    const float* states = (const float*)d_in[0];
    const float* embeds = (const float*)d_in[1];
    const int* span_starts = (const int*)d_in[2];
    const int* span_lengths = (const int*)d_in[3];
    const float* Wa1 = (const float*)d_in[4];
    const float* ba1 = (const float*)d_in[5];
    const float* Wa2 = (const float*)d_in[6];
    const float* ba2 = (const float*)d_in[7];
    const float* Wa3 = (const float*)d_in[8];
    const float* ba3 = (const float*)d_in[9];
    const float* width_table = (const float*)d_in[10];
    const float* Ws1 = (const float*)d_in[11];
    const float* bs1 = (const float*)d_in[12];
    const float* Ws2 = (const float*)d_in[13];
    const float* bs2 = (const float*)d_in[14];
    const float* Ws3 = (const float*)d_in[15];
    const float* bs3 = (const float*)d_in[16];
    float* out = (float*)d_out;

    // ---- workspace layout ----
    char* w = (char*)d_ws;
    unsigned short* WtA  = (unsigned short*)w;  w += 480 * 1024 * 2;
    unsigned short* WtE  = (unsigned short*)w;  w += 160 * 512 * 2;
    unsigned short* Wa2t = (unsigned short*)w;  w += 160 * 192 * 2;
    unsigned short* Ws2t = (unsigned short*)w;  w += 160 * 192 * 2;
    float* PW    = (float*)w;                   w += 5632;
    float* attns = (float*)w;                   w += 8192 * 4;
    unsigned short* Psh = (unsigned short*)w;   w += (size_t)T_TOK * 160 * 2;   // bf16
    unsigned short* Peh = (unsigned short*)w;   w += (size_t)T_TOK * 160 * 2;   // bf16
    unsigned short* Pmh = (unsigned short*)w;   w += (size_t)T_TOK * 160 * 2;   // bf16
    unsigned short* SH1 = (unsigned short*)w;   w += (size_t)S_SPAN * 192 * 2;  // bf16
    // No memsets: pad cols (0xAA poison = finite bf16) multiply zeroed W rows.

    // ---- prep: weight transposes + width proj (71 blocks) ----
    PrepTab pt;
    pt.g[0] = { Wa1,              WtA,              1024, 1024, (160*1024 + 255)/256 };
    pt.g[1] = { Ws1,              WtA + 160*1024,   1024, 1024, (160*1024 + 255)/256 };
    pt.g[2] = { Ws1 + 1024*150,   WtA + 320*1024,   1024, 1024, (160*1024 + 255)/256 };
    pt.g[3] = { Ws1 + 2048*150,   WtE,               512,  512, (160*512  + 255)/256 };
    pt.g[4] = { Wa2,              Wa2t,              150,  192, (160*192  + 255)/256 };
    pt.g[5] = { Ws2,              Ws2t,              150,  192, (160*192  + 255)/256 };
    pt.wt = width_table; pt.Ws1w = Ws1 + 2560*150; pt.PW = PW;
    int wblk = 0; for (int i = 0; i < 6; ++i) wblk += pt.g[i].nblk;
    prep_kernel<<<wblk + 9, 256, 0, stream>>>(pt);

    GG z = {};

    // ---- fused GEMM1+2 + attn layers 2/3: 4 groups, 512 blocks ----
    GTab t1; t1.ng = 4;
    t1.g[0] = z; t1.g[0].A = states; t1.g[0].lda = 1024; t1.g[0].W = WtA;            t1.g[0].K = 1024;
    t1.g[0].nrb = 128; t1.g[0].bias = ba1;
    t1.g[0].W2 = Wa2t; t1.g[0].bias2 = ba2;
    t1.g[0].dotv = Wa3; t1.g[0].dotb = ba3; t1.g[0].dotout = attns;
    t1.g[1] = z; t1.g[1].A = states; t1.g[1].lda = 1024; t1.g[1].W = WtA + 160*1024; t1.g[1].K = 1024;
    t1.g[1].nrb = 128; t1.g[1].outh = Psh; t1.g[1].ldo = 160;
    t1.g[2] = z; t1.g[2].A = states; t1.g[2].lda = 1024; t1.g[2].W = WtA + 320*1024; t1.g[2].K = 1024;
    t1.g[2].nrb = 128; t1.g[2].outh = Peh; t1.g[2].ldo = 160;
    t1.g[3] = z; t1.g[3].A = embeds; t1.g[3].lda = 512;  t1.g[3].W = WtE;            t1.g[3].K = 512;
    t1.g[3].nrb = 128; t1.g[3].outh = Pmh; t1.g[3].ldo = 160;
    gemm_fused<1, true><<<512, 256, 0, stream>>>(t1);

    // ---- span layer1 -> SH1 (bf16), 16 spans/block ----
    span_l1_kernel<<<S_SPAN / 16, 256, 0, stream>>>(attns, span_starts, span_lengths,
                                                    Psh, Peh, Pmh, PW, bs1, SH1);

    // ---- span layer2 + fused layer3 dot -> out ----
    GTab t3; t3.ng = 1;
    t3.g[0] = z; t3.g[0].A = SH1; t3.g[0].lda = 192; t3.g[0].W = Ws2t; t3.g[0].K = 192;
    t3.g[0].nrb = 512; t3.g[0].bias = bs2; t3.g[0].dotv = Ws3; t3.g[0].dotb = bs3; t3.g[0].dotout = out;
    gemm_fused<3, false><<<512, 256, 0, stream>>>(t3);
}

// Round 17
// 164.610 us; speedup vs baseline: 1.1571x; 1.0010x over previous
//
#include <hip/hip_runtime.h>
#include <math.h>

#define T_TOK 8192
#define A_DIM 1024
#define E_DIM 512
#define S_SPAN 32768
#define HID 150

typedef __attribute__((ext_vector_type(8))) short short8;
typedef __attribute__((ext_vector_type(4))) float f32x4;
typedef __attribute__((ext_vector_type(4))) unsigned int u32x4;

__device__ __forceinline__ unsigned short f2bf(float f) {
    unsigned int u = __builtin_bit_cast(unsigned int, f);
    u += 0x7FFFu + ((u >> 16) & 1u);          // RNE
    return (unsigned short)(u >> 16);
}
__device__ __forceinline__ float bf2f(unsigned int h16) {
    unsigned int u = h16 << 16;
    return __builtin_bit_cast(float, u);
}
__device__ __forceinline__ short8 cast8(f32x4 a, f32x4 b) {
    short8 r;
    r[0] = (short)f2bf(a.x); r[1] = (short)f2bf(a.y);
    r[2] = (short)f2bf(a.z); r[3] = (short)f2bf(a.w);
    r[4] = (short)f2bf(b.x); r[5] = (short)f2bf(b.y);
    r[6] = (short)f2bf(b.z); r[7] = (short)f2bf(b.w);
    return r;
}

// ---------------------------------------------------------------------------
// prep: 6 weight transposes + width projection (71 blocks; no input cast)
// ---------------------------------------------------------------------------
struct WConv { const float* src; unsigned short* dst; int K0; int Kpad; int nblk; };
struct PrepTab {
    WConv g[6];
    const float* wt; const float* Ws1w; float* PW;
};

__global__ __launch_bounds__(256) void prep_kernel(PrepTab tab) {
    int b = blockIdx.x;
    #pragma unroll
    for (int gi = 0; gi < 6; ++gi) {
        if (b < tab.g[gi].nblk) {
            int idx = b * 256 + threadIdx.x;               // idx = k*160 + j
            int Kpad = tab.g[gi].Kpad;
            if (idx < Kpad * 160) {
                int k = idx / 160, j = idx - k * 160;
                float v = (j < HID && k < tab.g[gi].K0)
                          ? tab.g[gi].src[(size_t)k * HID + j] : 0.f;   // coalesced read
                tab.g[gi].dst[(size_t)j * Kpad + k] = f2bf(v);          // scattered write
            }
            return;
        }
        b -= tab.g[gi].nblk;
    }
    // width projection: 9 blocks
    int j = threadIdx.x;
    if (j < HID) {
        float acc = 0.f;
        for (int k = 0; k < 20; ++k)
            acc = fmaf(tab.wt[b * 20 + k], tab.Ws1w[k * HID + j], acc);
        tab.PW[b * HID + j] = acc;
    }
}

// ---------------------------------------------------------------------------
// unified MFMA GEMM (R13 structure): dbuf BK=64, LDW=72 (46 KB, 3 blocks/CU).
// AF32: A fp32, cast to bf16 in-register AFTER the MFMA block.
// W2 path — fused attn layer2+3 in group-0 epilogue. h1 (16x160/wave)
// goes to a per-wave LDS tile (aliases WtL, dead after final barrier; no
// cross-wave sharing -> no barrier), re-read in MFMA A-layout, 5x10 MFMAs
// vs Wa2t, then dot epilogue -> attns. Bit-identical to a separate t2 dispatch
// (same bf16 rounding; old K=192 pad chunks added exact zeros).
// ---------------------------------------------------------------------------
struct GG {
    const void* A; int lda;
    const unsigned short* W; int K; int nrb;
    unsigned short* outh; int ldo;
    const float* bias; int relu;
    const float* dotv; const float* dotb; float* dotout;
    const unsigned short* W2; const float* bias2;
};
struct GTab { GG g[4]; int ng; };

template <int TAG, bool AF32>
__global__ __launch_bounds__(256) void gemm_fused(GTab tab) {
    constexpr int LDW = 72;
    __shared__ unsigned short WtL[2][160 * LDW];

    int b = blockIdx.x;
    int gi = 0;
    while (gi < tab.ng - 1 && b >= tab.g[gi].nrb) { b -= tab.g[gi].nrb; ++gi; }
    const GG G = tab.g[gi];

    const int tid = threadIdx.x;
    const int wid = tid >> 6;
    const int lane = tid & 63;
    const int l15 = lane & 15;
    const int quad = lane >> 4;
    const int row0 = b * 64 + wid * 16 + l15;
    const int K = G.K;
    const int nch = K >> 6;
    const float* Af = (const float*)G.A + (size_t)row0 * G.lda;
    const unsigned short* Ah = (const unsigned short*)G.A + (size_t)row0 * G.lda;

    u32x4 stg[5];
    int sn[5], sk[5];
    #pragma unroll
    for (int i = 0; i < 5; ++i) { int u = tid + i * 256; sn[i] = u >> 3; sk[i] = (u & 7) * 8; }

    f32x4 acc[10];
    #pragma unroll
    for (int nt = 0; nt < 10; ++nt) acc[nt] = (f32x4){0.f, 0.f, 0.f, 0.f};

    #pragma unroll
    for (int i = 0; i < 5; ++i)
        stg[i] = *(const u32x4*)(G.W + (size_t)sn[i] * K + sk[i]);
    short8 avc0, avc1;
    if (AF32) {
        f32x4 f0 = *(const f32x4*)(Af + quad * 8);
        f32x4 f1 = *(const f32x4*)(Af + quad * 8 + 4);
        f32x4 f2 = *(const f32x4*)(Af + 32 + quad * 8);
        f32x4 f3 = *(const f32x4*)(Af + 32 + quad * 8 + 4);
        avc0 = cast8(f0, f1);
        avc1 = cast8(f2, f3);
    } else {
        avc0 = *(const short8*)(Ah + quad * 8);
        avc1 = *(const short8*)(Ah + 32 + quad * 8);
    }
    #pragma unroll
    for (int i = 0; i < 5; ++i)
        *(u32x4*)&WtL[0][sn[i] * LDW + sk[i]] = stg[i];
    __syncthreads();

    for (int c = 0; c < nch; ++c) {
        const int pb = c & 1;
        short8 avn0, avn1;
        f32x4 fn0, fn1, fn2, fn3;
        const bool more = (c + 1 < nch);
        if (more) {
            const int kn = (c + 1) << 6;
            #pragma unroll
            for (int i = 0; i < 5; ++i)
                stg[i] = *(const u32x4*)(G.W + (size_t)sn[i] * K + kn + sk[i]);
            if (AF32) {
                fn0 = *(const f32x4*)(Af + kn + quad * 8);
                fn1 = *(const f32x4*)(Af + kn + quad * 8 + 4);
                fn2 = *(const f32x4*)(Af + kn + 32 + quad * 8);
                fn3 = *(const f32x4*)(Af + kn + 32 + quad * 8 + 4);
            } else {
                avn0 = *(const short8*)(Ah + kn + quad * 8);
                avn1 = *(const short8*)(Ah + kn + 32 + quad * 8);
            }
        }
        #pragma unroll
        for (int nt = 0; nt < 10; ++nt) {
            short8 bv0 = *(const short8*)&WtL[pb][(nt * 16 + l15) * LDW + quad * 8];
            acc[nt] = __builtin_amdgcn_mfma_f32_16x16x32_bf16(avc0, bv0, acc[nt], 0, 0, 0);
            short8 bv1 = *(const short8*)&WtL[pb][(nt * 16 + l15) * LDW + 32 + quad * 8];
            acc[nt] = __builtin_amdgcn_mfma_f32_16x16x32_bf16(avc1, bv1, acc[nt], 0, 0, 0);
        }
        if (more) {
            #pragma unroll
            for (int i = 0; i < 5; ++i)
                *(u32x4*)&WtL[pb ^ 1][sn[i] * LDW + sk[i]] = stg[i];
            if (AF32) {
                avc0 = cast8(fn0, fn1);
                avc1 = cast8(fn2, fn3);
            } else {
                avc0 = avn0; avc1 = avn1;
            }
        }
        __syncthreads();
    }

    const int rbase = b * 64 + wid * 16 + quad * 4;
    if (G.W2) {
        // ---- fused attn layer2+3 ----
        constexpr int LDH = 168;   // 336 B row stride, 16B-aligned
        unsigned short* tile = &WtL[0][0] + wid * 16 * LDH;   // per-wave region
        #pragma unroll
        for (int nt = 0; nt < 10; ++nt) {
            int col = nt * 16 + l15;
            float bv_ = (col < HID) ? G.bias[col] : 0.f;
            #pragma unroll
            for (int r = 0; r < 4; ++r) {
                float v = fmaxf(acc[nt][r] + bv_, 0.f);
                tile[(quad * 4 + r) * LDH + col] = f2bf(v);   // h1, C-layout write
            }
        }
        // same-wave RAW through LDS: compiler inserts lgkmcnt; no barrier.
        f32x4 acc2[10];
        #pragma unroll
        for (int nt = 0; nt < 10; ++nt) acc2[nt] = (f32x4){0.f, 0.f, 0.f, 0.f};
        #pragma unroll
        for (int kc = 0; kc < 5; ++kc) {
            short8 av = *(const short8*)&tile[l15 * LDH + kc * 32 + quad * 8];
            #pragma unroll
            for (int nt = 0; nt < 10; ++nt) {
                short8 bv = *(const short8*)(G.W2 + (size_t)(nt * 16 + l15) * 192 + kc * 32 + quad * 8);
                acc2[nt] = __builtin_amdgcn_mfma_f32_16x16x32_bf16(av, bv, acc2[nt], 0, 0, 0);
            }
        }
        float part[4] = {0.f, 0.f, 0.f, 0.f};
        #pragma unroll
        for (int nt = 0; nt < 10; ++nt) {
            int col = nt * 16 + l15;
            float b2 = (col < HID) ? G.bias2[col] : 0.f;
            float vv = (col < HID) ? G.dotv[col] : 0.f;
            #pragma unroll
            for (int r = 0; r < 4; ++r)
                part[r] += fmaxf(acc2[nt][r] + b2, 0.f) * vv;
        }
        #pragma unroll
        for (int r = 0; r < 4; ++r) {
            float p = part[r];
            #pragma unroll
            for (int off = 1; off < 16; off <<= 1) p += __shfl_xor(p, off);
            if (l15 == 0) G.dotout[rbase + r] = p + G.dotb[0];
        }
    } else if (G.dotout) {
        float part[4] = {0.f, 0.f, 0.f, 0.f};
        #pragma unroll
        for (int nt = 0; nt < 10; ++nt) {
            int col = nt * 16 + l15;
            float bv_ = (col < HID) ? G.bias[col] : 0.f;
            float vv = (col < HID) ? G.dotv[col] : 0.f;
            #pragma unroll
            for (int r = 0; r < 4; ++r)
                part[r] += fmaxf(acc[nt][r] + bv_, 0.f) * vv;
        }
        #pragma unroll
        for (int r = 0; r < 4; ++r) {
            float p = part[r];
            #pragma unroll
            for (int off = 1; off < 16; off <<= 1) p += __shfl_xor(p, off);
            if (l15 == 0) G.dotout[rbase + r] = p + G.dotb[0];
        }
    } else {
        #pragma unroll
        for (int nt = 0; nt < 10; ++nt) {
            int col = nt * 16 + l15;
            float bv_ = (G.bias != nullptr && col < HID) ? G.bias[col] : 0.f;
            #pragma unroll
            for (int r = 0; r < 4; ++r) {
                int row = rbase + r;
                float v = acc[nt][r] + bv_;
                if (G.relu) v = fmaxf(v, 0.f);
                G.outh[(size_t)row * G.ldo + col] = f2bf(v);
            }
        }
    }
}

// ---------------------------------------------------------------------------
// span layer-1: one span per 16-lane group (4/wave, 16/block).
// ---------------------------------------------------------------------------
__global__ __launch_bounds__(256) void span_l1_kernel(const float* __restrict__ attns,
                                                      const int* __restrict__ starts,
                                                      const int* __restrict__ lens,
                                                      const unsigned short* __restrict__ Ps,
                                                      const unsigned short* __restrict__ Pe,
                                                      const unsigned short* __restrict__ Pm,
                                                      const float* __restrict__ PW,
                                                      const float* __restrict__ bs1,
                                                      unsigned short* __restrict__ SH1) {
    const int wid = threadIdx.x >> 6;
    const int lane = threadIdx.x & 63;
    const int grp = lane >> 4;
    const int hl = lane & 15;
    const int gbase = lane & 48;
    const int s = blockIdx.x * 16 + wid * 4 + grp;
    const int start = starts[s];
    const int len = lens[s];

    const int iv = min(start + hl, T_TOK - 1);
    float a = (hl <= len) ? attns[iv] : -INFINITY;
    float m = a;
    #pragma unroll
    for (int off = 8; off; off >>= 1) m = fmaxf(m, __shfl_xor(m, off));
    float e = (hl <= len) ? __expf(a - m) : 0.f;
    float ssum = e;
    #pragma unroll
    for (int off = 8; off; off >>= 1) ssum += __shfl_xor(ssum, off);
    float wv = e / ssum;

    float wl[10]; int il[10];
    #pragma unroll
    for (int l = 0; l < 10; ++l) {
        wl[l] = __shfl(wv, gbase + l);
        il[l] = __shfl(iv, gbase + l);
    }

    const int end = start + len;
    const int width = len + 1;
    const int bucket = (width >= 1) + (width >= 2) + (width >= 3) + (width >= 4) +
                       (width >= 8) + (width >= 16) + (width >= 32) + (width >= 64);

    const unsigned short* ps = Ps + (size_t)start * 160;
    const unsigned short* pe = Pe + (size_t)end * 160;
    const float* pw = PW + bucket * HID;

    for (int p = hl; p < 75; p += 16) {
        const int j = 2 * p;
        unsigned int u0 = *(const unsigned int*)(ps + j);
        unsigned int u1 = *(const unsigned int*)(pe + j);
        float a0 = bs1[j]     + bf2f(u0 & 0xffff) + bf2f(u1 & 0xffff) + pw[j];
        float a1 = bs1[j + 1] + bf2f(u0 >> 16)    + bf2f(u1 >> 16)    + pw[j + 1];
        #pragma unroll
        for (int l = 0; l < 10; ++l) {
            unsigned int um = *(const unsigned int*)(Pm + (size_t)il[l] * 160 + j);
            a0 = fmaf(wl[l], bf2f(um & 0xffff), a0);
            a1 = fmaf(wl[l], bf2f(um >> 16), a1);
        }
        unsigned int packed = (unsigned int)f2bf(fmaxf(a0, 0.f)) |
                              ((unsigned int)f2bf(fmaxf(a1, 0.f)) << 16);
        *(unsigned int*)(SH1 + (size_t)s * 192 + j) = packed;
    }
}

extern "C" void kernel_launch(void* const* d_in, const int* in_sizes, int n_in,
                              void* d_out, int out_size, void* d_ws, size_t ws_size,
                              hipStream_t stream) {
    const float* states = (const float*)d_in[0];
    const float* embeds = (const float*)d_in[1];
    const int* span_starts = (const int*)d_in[2];
    const int* span_lengths = (const int*)d_in[3];
    const float* Wa1 = (const float*)d_in[4];
    const float* ba1 = (const float*)d_in[5];
    const float* Wa2 = (const float*)d_in[6];
    const float* ba2 = (const float*)d_in[7];
    const float* Wa3 = (const float*)d_in[8];
    const float* ba3 = (const float*)d_in[9];
    const float* width_table = (const float*)d_in[10];
    const float* Ws1 = (const float*)d_in[11];
    const float* bs1 = (const float*)d_in[12];
    const float* Ws2 = (const float*)d_in[13];
    const float* bs2 = (const float*)d_in[14];
    const float* Ws3 = (const float*)d_in[15];
    const float* bs3 = (const float*)d_in[16];
    float* out = (float*)d_out;

    // ---- workspace layout ----
    char* w = (char*)d_ws;
    unsigned short* WtA  = (unsigned short*)w;  w += 480 * 1024 * 2;
    unsigned short* WtE  = (unsigned short*)w;  w += 160 * 512 * 2;
    unsigned short* Wa2t = (unsigned short*)w;  w += 160 * 192 * 2;
    unsigned short* Ws2t = (unsigned short*)w;  w += 160 * 192 * 2;
    float* PW    = (float*)w;                   w += 5632;
    float* attns = (float*)w;                   w += 8192 * 4;
    unsigned short* Psh = (unsigned short*)w;   w += (size_t)T_TOK * 160 * 2;   // bf16
    unsigned short* Peh = (unsigned short*)w;   w += (size_t)T_TOK * 160 * 2;   // bf16
    unsigned short* Pmh = (unsigned short*)w;   w += (size_t)T_TOK * 160 * 2;   // bf16
    unsigned short* SH1 = (unsigned short*)w;   w += (size_t)S_SPAN * 192 * 2;  // bf16
    // No memsets: pad cols (0xAA poison = finite bf16) multiply zeroed W rows.

    // ---- prep: weight transposes + width proj (71 blocks) ----
    PrepTab pt;
    pt.g[0] = { Wa1,              WtA,              1024, 1024, (160*1024 + 255)/256 };
    pt.g[1] = { Ws1,              WtA + 160*1024,   1024, 1024, (160*1024 + 255)/256 };
    pt.g[2] = { Ws1 + 1024*150,   WtA + 320*1024,   1024, 1024, (160*1024 + 255)/256 };
    pt.g[3] = { Ws1 + 2048*150,   WtE,               512,  512, (160*512  + 255)/256 };
    pt.g[4] = { Wa2,              Wa2t,              150,  192, (160*192  + 255)/256 };
    pt.g[5] = { Ws2,              Ws2t,              150,  192, (160*192  + 255)/256 };
    pt.wt = width_table; pt.Ws1w = Ws1 + 2560*150; pt.PW = PW;
    int wblk = 0; for (int i = 0; i < 6; ++i) wblk += pt.g[i].nblk;
    prep_kernel<<<wblk + 9, 256, 0, stream>>>(pt);

    GG z = {};

    // ---- fused GEMM1+2 + attn layers 2/3: 4 groups, 512 blocks ----
    GTab t1; t1.ng = 4;
    t1.g[0] = z; t1.g[0].A = states; t1.g[0].lda = 1024; t1.g[0].W = WtA;            t1.g[0].K = 1024;
    t1.g[0].nrb = 128; t1.g[0].bias = ba1;
    t1.g[0].W2 = Wa2t; t1.g[0].bias2 = ba2;
    t1.g[0].dotv = Wa3; t1.g[0].dotb = ba3; t1.g[0].dotout = attns;
    t1.g[1] = z; t1.g[1].A = states; t1.g[1].lda = 1024; t1.g[1].W = WtA + 160*1024; t1.g[1].K = 1024;
    t1.g[1].nrb = 128; t1.g[1].outh = Psh; t1.g[1].ldo = 160;
    t1.g[2] = z; t1.g[2].A = states; t1.g[2].lda = 1024; t1.g[2].W = WtA + 320*1024; t1.g[2].K = 1024;
    t1.g[2].nrb = 128; t1.g[2].outh = Peh; t1.g[2].ldo = 160;
    t1.g[3] = z; t1.g[3].A = embeds; t1.g[3].lda = 512;  t1.g[3].W = WtE;            t1.g[3].K = 512;
    t1.g[3].nrb = 128; t1.g[3].outh = Pmh; t1.g[3].ldo = 160;
    gemm_fused<1, true><<<512, 256, 0, stream>>>(t1);

    // ---- span layer1 -> SH1 (bf16), 16 spans/block ----
    span_l1_kernel<<<S_SPAN / 16, 256, 0, stream>>>(attns, span_starts, span_lengths,
                                                    Psh, Peh, Pmh, PW, bs1, SH1);

    // ---- span layer2 + fused layer3 dot -> out ----
    GTab t3; t3.ng = 1;
    t3.g[0] = z; t3.g[0].A = SH1; t3.g[0].lda = 192; t3.g[0].W = Ws2t; t3.g[0].K = 192;
    t3.g[0].nrb = 512; t3.g[0].bias = bs2; t3.g[0].dotv = Ws3; t3.g[0].dotb = bs3; t3.g[0].dotout = out;
    gemm_fused<3, false><<<512, 256, 0, stream>>>(t3);
}